// Round 6
// baseline (190.835 us; speedup 1.0000x reference)
//
#include <hip/hip_runtime.h>
#include <hip/hip_bf16.h>
#include <math.h>

constexpr int B = 64, S = 512, D = 768, H1 = 256, H2 = 128;
constexpr float THR = 0.1f;

typedef short bf16x8 __attribute__((ext_vector_type(8)));
typedef float f32x4 __attribute__((ext_vector_type(4)));
typedef unsigned int uint_t;
typedef const __attribute__((address_space(1))) unsigned int* gptr_t;
typedef __attribute__((address_space(3))) unsigned int* lptr_t;

__device__ __forceinline__ unsigned short f2bf(float f) {
    unsigned int u = __builtin_bit_cast(unsigned int, f);
    unsigned int r = (u + 0x7FFFu + ((u >> 16) & 1u)) >> 16;
    return (unsigned short)r;
}
__device__ __forceinline__ float bf2f(unsigned short b) {
    return __builtin_bit_cast(float, (unsigned int)b << 16);
}
__device__ __forceinline__ void unpack8(const uint4& r, float* v) {
    v[0] = __builtin_bit_cast(float, r.x << 16); v[1] = __builtin_bit_cast(float, r.x & 0xFFFF0000u);
    v[2] = __builtin_bit_cast(float, r.y << 16); v[3] = __builtin_bit_cast(float, r.y & 0xFFFF0000u);
    v[4] = __builtin_bit_cast(float, r.z << 16); v[5] = __builtin_bit_cast(float, r.z & 0xFFFF0000u);
    v[6] = __builtin_bit_cast(float, r.w << 16); v[7] = __builtin_bit_cast(float, r.w & 0xFFFF0000u);
}
__device__ __forceinline__ void gl2lds16(const void* g, void* l) {
    __builtin_amdgcn_global_load_lds((gptr_t)g, (lptr_t)l, 16, 0, 0);
}

// ---------------- cast H fp32 -> bf16 (row-major [tok][D]) ----------------
__global__ __launch_bounds__(256) void k_cast(const float* __restrict__ in,
                                              short* __restrict__ out, int n8) {
    for (int i = blockIdx.x * 256 + threadIdx.x; i < n8; i += gridDim.x * 256) {
        float4 a = ((const float4*)in)[i * 2];
        float4 b = ((const float4*)in)[i * 2 + 1];
        uint4 o;
        o.x = (uint_t)f2bf(a.x) | ((uint_t)f2bf(a.y) << 16);
        o.y = (uint_t)f2bf(a.z) | ((uint_t)f2bf(a.w) << 16);
        o.z = (uint_t)f2bf(b.x) | ((uint_t)f2bf(b.y) << 16);
        o.w = (uint_t)f2bf(b.z) | ((uint_t)f2bf(b.w) << 16);
        ((uint4*)out)[i] = o;
    }
}

// ---------------- cast + transpose weights: in[K][N] -> out[N][K] bf16 ----------
__global__ __launch_bounds__(256) void k_castT(const float* __restrict__ in,
                                               short* __restrict__ out, int Kd, int Nd) {
    int idx = blockIdx.x * 256 + threadIdx.x;
    if (idx >= Kd * Nd) return;
    int n = idx / Kd, k = idx - n * Kd;
    out[idx] = (short)f2bf(in[(size_t)k * Nd + n]);
}

// ---------------- symmetric logits: expL tiles + atomic row-sums ----------------
// Upper-triangle 128x128 blocks only; mirror store goes through an LDS transpose
// (reusing the staging LDS) so both stores are vector-coalesced.
__global__ __launch_bounds__(256) void k_logits_sym(const short* __restrict__ Hb_,
                                                    short* __restrict__ L,
                                                    float* __restrict__ rsum) {
    const int bz = blockIdx.z;
    int p = blockIdx.x, bi = 0;
    while (p >= 4 - bi) { p -= 4 - bi; ++bi; }
    const int bj = bi + p;
    const short* Ab = Hb_ + (size_t)bz * S * D;
    short* Lb = L + (size_t)bz * S * S;
    float* rs = rsum + bz * S;
    const int M0 = bi * 128, N0 = bj * 128;

    __shared__ __align__(16) short smem[16384];  // As | Bs, reused for transpose
    short* As = smem;
    short* Bs = smem + 8192;

    const int tid = threadIdx.x, lane = tid & 63, wid = tid >> 6;
    const int wm = (wid & 1) * 64, wn = (wid >> 1) * 64;
    const int r_in = lane >> 3, kc = lane & 7;

    f32x4 zero = {0.f, 0.f, 0.f, 0.f};
    f32x4 acc[4][4];
    #pragma unroll
    for (int mi = 0; mi < 4; ++mi)
        #pragma unroll
        for (int nj = 0; nj < 4; ++nj) acc[mi][nj] = zero;

    for (int kt = 0; kt < D; kt += 64) {
        #pragma unroll
        for (int q = 0; q < 4; ++q) {
            const int ch = wid * 4 + q;
            gl2lds16(Ab + (size_t)(M0 + ch * 8 + r_in) * D + kt + kc * 8, &As[ch * 512]);
        }
        #pragma unroll
        for (int q = 0; q < 4; ++q) {
            const int ch = wid * 4 + q;
            gl2lds16(Ab + (size_t)(N0 + ch * 8 + r_in) * D + kt + kc * 8, &Bs[ch * 512]);
        }
        __syncthreads();
        #pragma unroll
        for (int kk = 0; kk < 2; ++kk) {
            bf16x8 af[4], bfr[4];
            const int co = kk * 32 + (lane >> 4) * 8;
            #pragma unroll
            for (int mi = 0; mi < 4; ++mi)
                af[mi] = *(const bf16x8*)&As[(wm + mi * 16 + (lane & 15)) * 64 + co];
            #pragma unroll
            for (int nj = 0; nj < 4; ++nj)
                bfr[nj] = *(const bf16x8*)&Bs[(wn + nj * 16 + (lane & 15)) * 64 + co];
            #pragma unroll
            for (int mi = 0; mi < 4; ++mi)
                #pragma unroll
                for (int nj = 0; nj < 4; ++nj)
                    acc[mi][nj] = __builtin_amdgcn_mfma_f32_16x16x32_bf16(
                        af[mi], bfr[nj], acc[mi][nj], 0, 0, 0);
        }
        __syncthreads();
    }

    // exp in place
    #pragma unroll
    for (int mi = 0; mi < 4; ++mi)
        #pragma unroll
        for (int nj = 0; nj < 4; ++nj) {
            f32x4 v = acc[mi][nj];
            acc[mi][nj][0] = __expf(v[0]);
            acc[mi][nj][1] = __expf(v[1]);
            acc[mi][nj][2] = __expf(v[2]);
            acc[mi][nj][3] = __expf(v[3]);
        }

    const bool mirror = (bi != bj);
    if (mirror) __syncthreads();  // staging LDS about to be reused

    // standard store [n][m] (+ stage transposed copy in LDS for the mirror)
    #pragma unroll
    for (int mi = 0; mi < 4; ++mi) {
        const int mb = wm + mi * 16 + (lane >> 4) * 4;
        #pragma unroll
        for (int nj = 0; nj < 4; ++nj) {
            const int n = wn + nj * 16 + (lane & 15);
            f32x4 v = acc[mi][nj];
            ushort4 o = make_ushort4(f2bf(v[0]), f2bf(v[1]), f2bf(v[2]), f2bf(v[3]));
            *(ushort4*)&Lb[(size_t)(N0 + n) * S + M0 + mb] = o;
            if (mirror) {
                smem[(mb + 0) * 128 + (n ^ (((mb + 0) & 7) << 3))] = (short)o.x;
                smem[(mb + 1) * 128 + (n ^ (((mb + 1) & 7) << 3))] = (short)o.y;
                smem[(mb + 2) * 128 + (n ^ (((mb + 2) & 7) << 3))] = (short)o.z;
                smem[(mb + 3) * 128 + (n ^ (((mb + 3) & 7) << 3))] = (short)o.w;
            }
        }
    }

    // col-partials: rsum[m] += sum over this tile's n
    #pragma unroll
    for (int mi = 0; mi < 4; ++mi)
        #pragma unroll
        for (int r = 0; r < 4; ++r) {
            float s = acc[mi][0][r] + acc[mi][1][r] + acc[mi][2][r] + acc[mi][3][r];
            s += __shfl_xor(s, 1); s += __shfl_xor(s, 2);
            s += __shfl_xor(s, 4); s += __shfl_xor(s, 8);
            if ((lane & 15) == 0)
                atomicAdd(&rs[M0 + wm + mi * 16 + (lane >> 4) * 4 + r], s);
        }

    if (mirror) {
        // row-partials (mirror contribution): rsum[n] += sum over this tile's m
        #pragma unroll
        for (int nj = 0; nj < 4; ++nj) {
            float s = 0.f;
            #pragma unroll
            for (int mi = 0; mi < 4; ++mi) {
                f32x4 v = acc[mi][nj];
                s += v[0] + v[1] + v[2] + v[3];
            }
            s += __shfl_xor(s, 16); s += __shfl_xor(s, 32);
            if (lane < 16)
                atomicAdd(&rs[N0 + wn + nj * 16 + lane], s);
        }
        __syncthreads();
        // coalesced mirror store [m][n] from transposed LDS
        #pragma unroll
        for (int it = 0; it < 8; ++it) {
            const int m = it * 16 + (tid >> 4);
            const int c = tid & 15;
            uint4 q = *(const uint4*)&smem[m * 128 + ((c * 8) ^ ((m & 7) << 3))];
            *(uint4*)&Lb[(size_t)(M0 + m) * S + N0 + c * 8] = q;
        }
    }
}

// ---------------- prep: deg -> dis, sparse wacc accumulation --------------------
__global__ __launch_bounds__(256) void k_prep(const short* __restrict__ L,
                                              const float* __restrict__ rsum,
                                              const int* __restrict__ mask,
                                              float* __restrict__ dis,
                                              float* __restrict__ wacc) {
    const int j = blockIdx.x * 4 + (threadIdx.x >> 6);  // b*S + jl
    const int lane = threadIdx.x & 63;
    const int b = j >> 9, jl = j & (S - 1);
    const size_t base = (size_t)b * S * S + (size_t)jl * S + lane * 8;
    uint4 r = *(const uint4*)(L + base);
    float v[8];
    unpack8(r, v);
    const int i0 = lane * 8;
    const float4 sa = *(const float4*)&rsum[b * S + i0];
    const float4 sb = *(const float4*)&rsum[b * S + i0 + 4];
    const float rsv[8] = {sa.x, sa.y, sa.z, sa.w, sb.x, sb.y, sb.z, sb.w};
    float a[8];
    float deg = 0.f;
    #pragma unroll
    for (int e = 0; e < 8; ++e) {
        float att = v[e] / rsv[e];   // att[i][j], i = i0+e
        if (i0 + e == jl) a[e] = (att > THR) ? att : 1.0f;
        else              a[e] = (att > THR) ? att : 0.0f;
        deg += a[e];
    }
    #pragma unroll
    for (int off = 1; off < 64; off <<= 1) deg += __shfl_xor(deg, off);
    const float d = (deg > 0.f) ? rsqrtf(deg) : 0.f;
    const float cv = d * (float)mask[j];
    if (lane == 0) dis[j] = d;
    #pragma unroll
    for (int e = 0; e < 8; ++e)
        if (a[e] != 0.f) atomicAdd(&wacc[b * S + i0 + e], cv * a[e]);
}

// ---------------- sparse aggregation: y1[j][h] = relu(dis_j*sum + b1[h]) --------
// One block per target j; recompute a[i][j] from expL row, gather nonzero sources.
__global__ __launch_bounds__(256) void k_agg(const short* __restrict__ L,
                                             const float* __restrict__ rsum,
                                             const float* __restrict__ dis,
                                             const short* __restrict__ xw1d,
                                             const float* __restrict__ b1,
                                             short* __restrict__ y1) {
    const int j = blockIdx.x;            // b*S + jl
    const int b = j >> 9, jl = j & (S - 1);
    const int tid = threadIdx.x;
    __shared__ float ew[S];
    __shared__ uint_t msk[S / 32];
    if (tid < S / 32) msk[tid] = 0;
    __syncthreads();
    {
        const int i0 = tid * 2;
        const uint_t v = *(const uint_t*)(L + (size_t)b * S * S + (size_t)jl * S + i0);
        const float e0 = bf2f((unsigned short)(v & 0xFFFFu));
        const float e1 = bf2f((unsigned short)(v >> 16));
        const float2 rsp = *(const float2*)&rsum[b * S + i0];
        const float att0 = e0 / rsp.x, att1 = e1 / rsp.y;
        const float a0 = (att0 > THR) ? att0 : ((i0 == jl) ? 1.f : 0.f);
        const float a1 = (att1 > THR) ? att1 : ((i0 + 1 == jl) ? 1.f : 0.f);
        ew[i0] = a0;
        ew[i0 + 1] = a1;
        const uint_t bits = (a0 != 0.f ? 1u : 0u) | (a1 != 0.f ? 2u : 0u);
        if (bits) atomicOr(&msk[i0 >> 5], bits << (i0 & 31));
    }
    __syncthreads();
    const int h = tid;
    float acc = 0.f;
    #pragma unroll 1
    for (int g = 0; g < S / 32; ++g) {
        uint_t m = msk[g];
        while (m) {
            const int bpos = __builtin_ctz(m);
            m &= m - 1;
            const int i = g * 32 + bpos;
            acc += ew[i] * bf2f((unsigned short)xw1d[(size_t)(b * S + i) * H1 + h]);
        }
    }
    const float val = fmaxf(dis[j] * acc + b1[h], 0.f);
    y1[(size_t)j * H1 + h] = (short)f2bf(val);
}

// ---------------- generic NT-GEMM, bf16 MFMA, C stored [N][M] bf16 --------------
// MODE 0: plain; 3: v * sN[n]
template <int MODE>
__global__ __launch_bounds__(256) void k_gemm_nt(
    const short* __restrict__ A, const short* __restrict__ Bm, short* __restrict__ C,
    int K, int lda, int ldb, int ldc,
    const float* __restrict__ sN) {
    const int M0 = blockIdx.x * 128, N0 = blockIdx.y * 128;

    __shared__ __align__(16) short As[128 * 64];
    __shared__ __align__(16) short Bs[128 * 64];

    const int tid = threadIdx.x, lane = tid & 63, wid = tid >> 6;
    const int wm = (wid & 1) * 64, wn = (wid >> 1) * 64;
    const int r_in = lane >> 3, kc = lane & 7;

    f32x4 zero = {0.f, 0.f, 0.f, 0.f};
    f32x4 acc[4][4];
    #pragma unroll
    for (int mi = 0; mi < 4; ++mi)
        #pragma unroll
        for (int nj = 0; nj < 4; ++nj) acc[mi][nj] = zero;

    for (int kt = 0; kt < K; kt += 64) {
        #pragma unroll
        for (int q = 0; q < 4; ++q) {
            const int ch = wid * 4 + q;
            gl2lds16(A + (size_t)(M0 + ch * 8 + r_in) * lda + kt + kc * 8, &As[ch * 512]);
        }
        #pragma unroll
        for (int q = 0; q < 4; ++q) {
            const int ch = wid * 4 + q;
            gl2lds16(Bm + (size_t)(N0 + ch * 8 + r_in) * ldb + kt + kc * 8, &Bs[ch * 512]);
        }
        __syncthreads();
        #pragma unroll
        for (int kk = 0; kk < 2; ++kk) {
            bf16x8 af[4], bfr[4];
            const int co = kk * 32 + (lane >> 4) * 8;
            #pragma unroll
            for (int mi = 0; mi < 4; ++mi)
                af[mi] = *(const bf16x8*)&As[(wm + mi * 16 + (lane & 15)) * 64 + co];
            #pragma unroll
            for (int nj = 0; nj < 4; ++nj)
                bfr[nj] = *(const bf16x8*)&Bs[(wn + nj * 16 + (lane & 15)) * 64 + co];
            #pragma unroll
            for (int mi = 0; mi < 4; ++mi)
                #pragma unroll
                for (int nj = 0; nj < 4; ++nj)
                    acc[mi][nj] = __builtin_amdgcn_mfma_f32_16x16x32_bf16(
                        af[mi], bfr[nj], acc[mi][nj], 0, 0, 0);
        }
        __syncthreads();
    }

    #pragma unroll
    for (int mi = 0; mi < 4; ++mi) {
        const int m = M0 + wm + mi * 16 + (lane >> 4) * 4;
        #pragma unroll
        for (int nj = 0; nj < 4; ++nj) {
            const int n = N0 + wn + nj * 16 + (lane & 15);
            f32x4 v = acc[mi][nj];
            float o0 = v[0], o1 = v[1], o2 = v[2], o3 = v[3];
            if (MODE == 3) {
                const float sn = sN[n];
                o0 *= sn; o1 *= sn; o2 *= sn; o3 *= sn;
            }
            ushort4 o = make_ushort4(f2bf(o0), f2bf(o1), f2bf(o2), f2bf(o3));
            *(ushort4*)&C[(size_t)n * ldc + m] = o;
        }
    }
}

// ---------------- final: weighted colsum of xw2T + head -------------------------
__global__ __launch_bounds__(128) void k_final(const short* __restrict__ xw2T,
                                               const float* __restrict__ wacc,
                                               const float* __restrict__ dis,
                                               const int* __restrict__ mask,
                                               const float* __restrict__ b2,
                                               const float* __restrict__ Wc,
                                               const float* __restrict__ bc,
                                               float* __restrict__ out) {
    const int b = blockIdx.x;
    const int h = threadIdx.x;  // 0..127
    const short* xrow = xw2T + (size_t)h * (B * S) + b * S;
    const float* wa = wacc + b * S;
    const float* db = dis + b * S;
    const int* mb = mask + b * S;

    float acc = 0.f;
    for (int t = 0; t < S; t += 8) {
        uint4 r = *(const uint4*)&xrow[t];
        float v[8];
        unpack8(r, v);
        const float4 w0 = *(const float4*)&wa[t];
        const float4 w1 = *(const float4*)&wa[t + 4];
        const float4 d0 = *(const float4*)&db[t];
        const float4 d1 = *(const float4*)&db[t + 4];
        acc += v[0] * w0.x * d0.x + v[1] * w0.y * d0.y +
               v[2] * w0.z * d0.z + v[3] * w0.w * d0.w;
        acc += v[4] * w1.x * d1.x + v[5] * w1.y * d1.y +
               v[6] * w1.z * d1.z + v[7] * w1.w * d1.w;
    }

    float msum = 0.f;
    for (int i = h; i < S; i += 128) msum += (float)mb[i];
    #pragma unroll
    for (int off = 1; off < 64; off <<= 1) msum += __shfl_xor(msum, off);
    __shared__ float redm[2], redv[2];
    if ((h & 63) == 0) redm[h >> 6] = msum;
    __syncthreads();
    msum = redm[0] + redm[1];

    const float e = b2[h] + acc / msum;
    float val = e * Wc[h];
    #pragma unroll
    for (int off = 1; off < 64; off <<= 1) val += __shfl_xor(val, off);
    if ((h & 63) == 0) redv[h >> 6] = val;
    __syncthreads();
    if (h == 0) {
        float z = redv[0] + redv[1] + bc[0];
        out[b] = 1.f / (1.f + expf(-z));
    }
}

extern "C" void kernel_launch(void* const* d_in, const int* in_sizes, int n_in,
                              void* d_out, int out_size, void* d_ws, size_t ws_size,
                              hipStream_t stream) {
    const float* H    = (const float*)d_in[0];
    const int*   mask = (const int*)d_in[1];
    const float* W1   = (const float*)d_in[2];
    const float* b1   = (const float*)d_in[3];
    const float* W2   = (const float*)d_in[4];
    const float* b2   = (const float*)d_in[5];
    const float* Wc   = (const float*)d_in[6];
    const float* bc   = (const float*)d_in[7];
    float* out = (float*)d_out;

    const int NTOK = B * S;  // 32768

    // workspace layout (bytes)
    char* wsb = (char*)d_ws;
    short* Hb    = (short*)(wsb);                       // 25165824 el (48 MB)
    short* y1    = (short*)(wsb);                       // overlays Hb (dead by then)
    short* Lbuf  = (short*)(wsb + 50331648);            // 16777216 el (32 MB)
    short* xw1d  = (short*)(wsb + 83886080);            // 8388608 el (16 MB)
    short* xw2T  = (short*)(wsb + 100663296);           // 4194304 el (8 MB)
    float* rsum  = (float*)(wsb + 109051904);           // 32768 f
    float* wacc  = rsum + NTOK;                         // 32768 f (contiguous)
    float* dis   = wacc + NTOK;                         // 32768 f
    short* W1T   = (short*)(dis + NTOK);                // 196608 el
    short* W2T   = W1T + 196608;                        // 32768 el

    (void)hipMemsetAsync(rsum, 0, 2 * NTOK * sizeof(float), stream);  // rsum + wacc

    k_cast<<<2048, 256, 0, stream>>>(H, Hb, NTOK * D / 8);
    k_castT<<<768, 256, 0, stream>>>(W1, W1T, D, H1);
    k_castT<<<128, 256, 0, stream>>>(W2, W2T, H1, H2);

    // expL (symmetric, upper blocks, coalesced mirror) + row sums
    k_logits_sym<<<dim3(10, 1, B), 256, 0, stream>>>(Hb, Lbuf, rsum);

    // deg -> dis, sparse wacc
    k_prep<<<NTOK / 4, 256, 0, stream>>>(Lbuf, rsum, mask, dis, wacc);

    // xw1d[tok][h1] = dis_tok * (H @ W1)[tok][h1]  (operands swapped: M=H1, N=NTOK)
    k_gemm_nt<3><<<dim3(H1 / 128, NTOK / 128, 1), 256, 0, stream>>>(
        W1T, Hb, xw1d, D, D, D, H1, dis);

    // sparse aggregation + relu + bias
    k_agg<<<NTOK, 256, 0, stream>>>(Lbuf, rsum, dis, xw1d, b1, y1);

    // xw2T[h2][tok] = (y1 @ W2)[tok][h2]   (M=NTOK, N=H2, K=H1)
    k_gemm_nt<0><<<dim3(NTOK / 128, H2 / 128, 1), 256, 0, stream>>>(
        y1, W2T, xw2T, H1, H1, H1, NTOK, nullptr);

    k_final<<<B, 128, 0, stream>>>(xw2T, wacc, dis, mask, b2, Wc, bc, out);
}

// Round 7
// 189.179 us; speedup vs baseline: 1.0088x; 1.0088x over previous
//
#include <hip/hip_runtime.h>
#include <hip/hip_bf16.h>
#include <math.h>

constexpr int B = 64, S = 512, D = 768, H1 = 256, H2 = 128;
constexpr float THR = 0.1f;

typedef short bf16x8 __attribute__((ext_vector_type(8)));
typedef float f32x4 __attribute__((ext_vector_type(4)));
typedef unsigned int uint_t;
typedef const __attribute__((address_space(1))) unsigned int* gptr_t;
typedef __attribute__((address_space(3))) unsigned int* lptr_t;

__device__ __forceinline__ unsigned short f2bf(float f) {
    unsigned int u = __builtin_bit_cast(unsigned int, f);
    unsigned int r = (u + 0x7FFFu + ((u >> 16) & 1u)) >> 16;
    return (unsigned short)r;
}
__device__ __forceinline__ float bf2f(unsigned short b) {
    return __builtin_bit_cast(float, (unsigned int)b << 16);
}
__device__ __forceinline__ void unpack8(const uint4& r, float* v) {
    v[0] = __builtin_bit_cast(float, r.x << 16); v[1] = __builtin_bit_cast(float, r.x & 0xFFFF0000u);
    v[2] = __builtin_bit_cast(float, r.y << 16); v[3] = __builtin_bit_cast(float, r.y & 0xFFFF0000u);
    v[4] = __builtin_bit_cast(float, r.z << 16); v[5] = __builtin_bit_cast(float, r.z & 0xFFFF0000u);
    v[6] = __builtin_bit_cast(float, r.w << 16); v[7] = __builtin_bit_cast(float, r.w & 0xFFFF0000u);
}
__device__ __forceinline__ void gl2lds16(const void* g, void* l) {
    __builtin_amdgcn_global_load_lds((gptr_t)g, (lptr_t)l, 16, 0, 0);
}

// ---------------- cast H fp32 -> bf16 (row-major [tok][D]) ----------------
__global__ __launch_bounds__(256) void k_cast(const float* __restrict__ in,
                                              short* __restrict__ out, int n8) {
    for (int i = blockIdx.x * 256 + threadIdx.x; i < n8; i += gridDim.x * 256) {
        float4 a = ((const float4*)in)[i * 2];
        float4 b = ((const float4*)in)[i * 2 + 1];
        uint4 o;
        o.x = (uint_t)f2bf(a.x) | ((uint_t)f2bf(a.y) << 16);
        o.y = (uint_t)f2bf(a.z) | ((uint_t)f2bf(a.w) << 16);
        o.z = (uint_t)f2bf(b.x) | ((uint_t)f2bf(b.y) << 16);
        o.w = (uint_t)f2bf(b.z) | ((uint_t)f2bf(b.w) << 16);
        ((uint4*)out)[i] = o;
    }
}

// ---------------- cast + transpose weights: in[K][N] -> out[N][K] bf16 ----------
__global__ __launch_bounds__(256) void k_castT(const float* __restrict__ in,
                                               short* __restrict__ out, int Kd, int Nd) {
    int idx = blockIdx.x * 256 + threadIdx.x;
    if (idx >= Kd * Nd) return;
    int n = idx / Kd, k = idx - n * Kd;
    out[idx] = (short)f2bf(in[(size_t)k * Nd + n]);
}

// ---------------- symmetric logits: expL tiles + atomic row-sums ----------------
// Upper-triangle 128x128 blocks; K-loop double-buffered (prefetch t+1 before
// computing t); XCD-swizzled flat grid; mirror store via LDS transpose.
__global__ __launch_bounds__(256) void k_logits_sym(const short* __restrict__ Hb_,
                                                    short* __restrict__ L,
                                                    float* __restrict__ rsum) {
    // bijective XCD swizzle: 640 wgs = 8 XCDs x 80; each XCD gets 8 whole batches
    const int orig = blockIdx.x;
    const int wg = (orig & 7) * 80 + (orig >> 3);
    const int bz = wg / 10;
    int p = wg - bz * 10, bi = 0;
    while (p >= 4 - bi) { p -= 4 - bi; ++bi; }
    const int bj = bi + p;
    const short* Ab = Hb_ + (size_t)bz * S * D;
    short* Lb = L + (size_t)bz * S * S;
    float* rs = rsum + bz * S;
    const int M0 = bi * 128, N0 = bj * 128;

    __shared__ __align__(16) short As[2][8192];
    __shared__ __align__(16) short Bs[2][8192];

    const int tid = threadIdx.x, lane = tid & 63, wid = tid >> 6;
    const int wm = (wid & 1) * 64, wn = (wid >> 1) * 64;
    const int r_in = lane >> 3, kc = lane & 7;

    auto stage = [&](int buf, int kt) {
        #pragma unroll
        for (int q = 0; q < 4; ++q) {
            const int ch = wid * 4 + q;
            gl2lds16(Ab + (size_t)(M0 + ch * 8 + r_in) * D + kt + kc * 8, &As[buf][ch * 512]);
        }
        #pragma unroll
        for (int q = 0; q < 4; ++q) {
            const int ch = wid * 4 + q;
            gl2lds16(Ab + (size_t)(N0 + ch * 8 + r_in) * D + kt + kc * 8, &Bs[buf][ch * 512]);
        }
    };

    f32x4 zero = {0.f, 0.f, 0.f, 0.f};
    f32x4 acc[4][4];
    #pragma unroll
    for (int mi = 0; mi < 4; ++mi)
        #pragma unroll
        for (int nj = 0; nj < 4; ++nj) acc[mi][nj] = zero;

    stage(0, 0);
    __syncthreads();
    int cur = 0;
    for (int t = 0; t < 12; ++t) {
        if (t < 11) stage(cur ^ 1, (t + 1) * 64);   // prefetch next K-tile
        #pragma unroll
        for (int kk = 0; kk < 2; ++kk) {
            bf16x8 af[4], bfr[4];
            const int co = kk * 32 + (lane >> 4) * 8;
            #pragma unroll
            for (int mi = 0; mi < 4; ++mi)
                af[mi] = *(const bf16x8*)&As[cur][(wm + mi * 16 + (lane & 15)) * 64 + co];
            #pragma unroll
            for (int nj = 0; nj < 4; ++nj)
                bfr[nj] = *(const bf16x8*)&Bs[cur][(wn + nj * 16 + (lane & 15)) * 64 + co];
            #pragma unroll
            for (int mi = 0; mi < 4; ++mi)
                #pragma unroll
                for (int nj = 0; nj < 4; ++nj)
                    acc[mi][nj] = __builtin_amdgcn_mfma_f32_16x16x32_bf16(
                        af[mi], bfr[nj], acc[mi][nj], 0, 0, 0);
        }
        __syncthreads();   // drains prefetch (latency hidden under compute above)
        cur ^= 1;
    }

    // exp in place
    #pragma unroll
    for (int mi = 0; mi < 4; ++mi)
        #pragma unroll
        for (int nj = 0; nj < 4; ++nj) {
            f32x4 v = acc[mi][nj];
            acc[mi][nj][0] = __expf(v[0]);
            acc[mi][nj][1] = __expf(v[1]);
            acc[mi][nj][2] = __expf(v[2]);
            acc[mi][nj][3] = __expf(v[3]);
        }

    const bool mirror = (bi != bj);
    short* smem = &As[0][0];   // 32KB transpose scratch (compute done, post-barrier)

    // standard store [n][m] (+ stage transposed copy in LDS for the mirror)
    #pragma unroll
    for (int mi = 0; mi < 4; ++mi) {
        const int mb = wm + mi * 16 + (lane >> 4) * 4;
        #pragma unroll
        for (int nj = 0; nj < 4; ++nj) {
            const int n = wn + nj * 16 + (lane & 15);
            f32x4 v = acc[mi][nj];
            ushort4 o = make_ushort4(f2bf(v[0]), f2bf(v[1]), f2bf(v[2]), f2bf(v[3]));
            *(ushort4*)&Lb[(size_t)(N0 + n) * S + M0 + mb] = o;
            if (mirror) {
                smem[(mb + 0) * 128 + (n ^ (((mb + 0) & 7) << 3))] = (short)o.x;
                smem[(mb + 1) * 128 + (n ^ (((mb + 1) & 7) << 3))] = (short)o.y;
                smem[(mb + 2) * 128 + (n ^ (((mb + 2) & 7) << 3))] = (short)o.z;
                smem[(mb + 3) * 128 + (n ^ (((mb + 3) & 7) << 3))] = (short)o.w;
            }
        }
    }

    // col-partials: rsum[m] += sum over this tile's n
    #pragma unroll
    for (int mi = 0; mi < 4; ++mi)
        #pragma unroll
        for (int r = 0; r < 4; ++r) {
            float s = acc[mi][0][r] + acc[mi][1][r] + acc[mi][2][r] + acc[mi][3][r];
            s += __shfl_xor(s, 1); s += __shfl_xor(s, 2);
            s += __shfl_xor(s, 4); s += __shfl_xor(s, 8);
            if ((lane & 15) == 0)
                atomicAdd(&rs[M0 + wm + mi * 16 + (lane >> 4) * 4 + r], s);
        }

    if (mirror) {
        // row-partials (mirror contribution): rsum[n] += sum over this tile's m
        #pragma unroll
        for (int nj = 0; nj < 4; ++nj) {
            float s = 0.f;
            #pragma unroll
            for (int mi = 0; mi < 4; ++mi) {
                f32x4 v = acc[mi][nj];
                s += v[0] + v[1] + v[2] + v[3];
            }
            s += __shfl_xor(s, 16); s += __shfl_xor(s, 32);
            if (lane < 16)
                atomicAdd(&rs[N0 + wn + nj * 16 + lane], s);
        }
        __syncthreads();
        // coalesced mirror store [m][n] from transposed LDS
        #pragma unroll
        for (int it = 0; it < 8; ++it) {
            const int m = it * 16 + (tid >> 4);
            const int c = tid & 15;
            uint4 q = *(const uint4*)&smem[m * 128 + ((c * 8) ^ ((m & 7) << 3))];
            *(uint4*)&Lb[(size_t)(M0 + m) * S + N0 + c * 8] = q;
        }
    }
}

// ---------------- prep: deg -> dis, sparse wacc accumulation --------------------
__global__ __launch_bounds__(256) void k_prep(const short* __restrict__ L,
                                              const float* __restrict__ rsum,
                                              const int* __restrict__ mask,
                                              float* __restrict__ dis,
                                              float* __restrict__ wacc) {
    const int j = blockIdx.x * 4 + (threadIdx.x >> 6);  // b*S + jl
    const int lane = threadIdx.x & 63;
    const int b = j >> 9, jl = j & (S - 1);
    const size_t base = (size_t)b * S * S + (size_t)jl * S + lane * 8;
    uint4 r = *(const uint4*)(L + base);
    float v[8];
    unpack8(r, v);
    const int i0 = lane * 8;
    const float4 sa = *(const float4*)&rsum[b * S + i0];
    const float4 sb = *(const float4*)&rsum[b * S + i0 + 4];
    const float rsv[8] = {sa.x, sa.y, sa.z, sa.w, sb.x, sb.y, sb.z, sb.w};
    float a[8];
    float deg = 0.f;
    #pragma unroll
    for (int e = 0; e < 8; ++e) {
        float att = v[e] / rsv[e];   // att[i][j], i = i0+e
        if (i0 + e == jl) a[e] = (att > THR) ? att : 1.0f;
        else              a[e] = (att > THR) ? att : 0.0f;
        deg += a[e];
    }
    #pragma unroll
    for (int off = 1; off < 64; off <<= 1) deg += __shfl_xor(deg, off);
    const float d = (deg > 0.f) ? rsqrtf(deg) : 0.f;
    const float cv = d * (float)mask[j];
    if (lane == 0) dis[j] = d;
    #pragma unroll
    for (int e = 0; e < 8; ++e)
        if (a[e] != 0.f) atomicAdd(&wacc[b * S + i0 + e], cv * a[e]);
}

// ---------------- sparse aggregation: y1[j][h] = relu(dis_j*sum + b1[h]) --------
__global__ __launch_bounds__(256) void k_agg(const short* __restrict__ L,
                                             const float* __restrict__ rsum,
                                             const float* __restrict__ dis,
                                             const short* __restrict__ xw1d,
                                             const float* __restrict__ b1,
                                             short* __restrict__ y1) {
    const int j = blockIdx.x;            // b*S + jl
    const int b = j >> 9, jl = j & (S - 1);
    const int tid = threadIdx.x;
    __shared__ float ew[S];
    __shared__ uint_t msk[S / 32];
    if (tid < S / 32) msk[tid] = 0;
    __syncthreads();
    {
        const int i0 = tid * 2;
        const uint_t v = *(const uint_t*)(L + (size_t)b * S * S + (size_t)jl * S + i0);
        const float e0 = bf2f((unsigned short)(v & 0xFFFFu));
        const float e1 = bf2f((unsigned short)(v >> 16));
        const float2 rsp = *(const float2*)&rsum[b * S + i0];
        const float att0 = e0 / rsp.x, att1 = e1 / rsp.y;
        const float a0 = (att0 > THR) ? att0 : ((i0 == jl) ? 1.f : 0.f);
        const float a1 = (att1 > THR) ? att1 : ((i0 + 1 == jl) ? 1.f : 0.f);
        ew[i0] = a0;
        ew[i0 + 1] = a1;
        const uint_t bits = (a0 != 0.f ? 1u : 0u) | (a1 != 0.f ? 2u : 0u);
        if (bits) atomicOr(&msk[i0 >> 5], bits << (i0 & 31));
    }
    __syncthreads();
    const int h = tid;
    float acc = 0.f;
    #pragma unroll 1
    for (int g = 0; g < S / 32; ++g) {
        uint_t m = msk[g];
        while (m) {
            const int bpos = __builtin_ctz(m);
            m &= m - 1;
            const int i = g * 32 + bpos;
            acc += ew[i] * bf2f((unsigned short)xw1d[(size_t)(b * S + i) * H1 + h]);
        }
    }
    const float val = fmaxf(dis[j] * acc + b1[h], 0.f);
    y1[(size_t)j * H1 + h] = (short)f2bf(val);
}

// ---------------- generic NT-GEMM, bf16 MFMA, double-buffered, C [N][M] bf16 ----
// MODE 0: plain; 3: v * sN[n]
template <int MODE>
__global__ __launch_bounds__(256) void k_gemm_nt(
    const short* __restrict__ A, const short* __restrict__ Bm, short* __restrict__ C,
    int K, int lda, int ldb, int ldc,
    const float* __restrict__ sN) {
    const int M0 = blockIdx.x * 128, N0 = blockIdx.y * 128;

    __shared__ __align__(16) short As[2][8192];
    __shared__ __align__(16) short Bs[2][8192];

    const int tid = threadIdx.x, lane = tid & 63, wid = tid >> 6;
    const int wm = (wid & 1) * 64, wn = (wid >> 1) * 64;
    const int r_in = lane >> 3, kc = lane & 7;

    auto stage = [&](int buf, int kt) {
        #pragma unroll
        for (int q = 0; q < 4; ++q) {
            const int ch = wid * 4 + q;
            gl2lds16(A + (size_t)(M0 + ch * 8 + r_in) * lda + kt + kc * 8, &As[buf][ch * 512]);
        }
        #pragma unroll
        for (int q = 0; q < 4; ++q) {
            const int ch = wid * 4 + q;
            gl2lds16(Bm + (size_t)(N0 + ch * 8 + r_in) * ldb + kt + kc * 8, &Bs[buf][ch * 512]);
        }
    };

    f32x4 zero = {0.f, 0.f, 0.f, 0.f};
    f32x4 acc[4][4];
    #pragma unroll
    for (int mi = 0; mi < 4; ++mi)
        #pragma unroll
        for (int nj = 0; nj < 4; ++nj) acc[mi][nj] = zero;

    const int nt = K >> 6;
    stage(0, 0);
    __syncthreads();
    int cur = 0;
    for (int t = 0; t < nt; ++t) {
        if (t + 1 < nt) stage(cur ^ 1, (t + 1) << 6);
        #pragma unroll
        for (int kk = 0; kk < 2; ++kk) {
            bf16x8 af[4], bfr[4];
            const int co = kk * 32 + (lane >> 4) * 8;
            #pragma unroll
            for (int mi = 0; mi < 4; ++mi)
                af[mi] = *(const bf16x8*)&As[cur][(wm + mi * 16 + (lane & 15)) * 64 + co];
            #pragma unroll
            for (int nj = 0; nj < 4; ++nj)
                bfr[nj] = *(const bf16x8*)&Bs[cur][(wn + nj * 16 + (lane & 15)) * 64 + co];
            #pragma unroll
            for (int mi = 0; mi < 4; ++mi)
                #pragma unroll
                for (int nj = 0; nj < 4; ++nj)
                    acc[mi][nj] = __builtin_amdgcn_mfma_f32_16x16x32_bf16(
                        af[mi], bfr[nj], acc[mi][nj], 0, 0, 0);
        }
        __syncthreads();
        cur ^= 1;
    }

    #pragma unroll
    for (int mi = 0; mi < 4; ++mi) {
        const int m = M0 + wm + mi * 16 + (lane >> 4) * 4;
        #pragma unroll
        for (int nj = 0; nj < 4; ++nj) {
            const int n = N0 + wn + nj * 16 + (lane & 15);
            f32x4 v = acc[mi][nj];
            float o0 = v[0], o1 = v[1], o2 = v[2], o3 = v[3];
            if (MODE == 3) {
                const float sn = sN[n];
                o0 *= sn; o1 *= sn; o2 *= sn; o3 *= sn;
            }
            ushort4 o = make_ushort4(f2bf(o0), f2bf(o1), f2bf(o2), f2bf(o3));
            *(ushort4*)&C[(size_t)n * ldc + m] = o;
        }
    }
}

// ---------------- final: weighted colsum of xw2[tok][H2] + head -----------------
__global__ __launch_bounds__(128) void k_final(const short* __restrict__ xw2,
                                               const float* __restrict__ wacc,
                                               const float* __restrict__ dis,
                                               const int* __restrict__ mask,
                                               const float* __restrict__ b2,
                                               const float* __restrict__ Wc,
                                               const float* __restrict__ bc,
                                               float* __restrict__ out) {
    const int b = blockIdx.x;
    const int h = threadIdx.x;  // 0..127
    const short* xb = xw2 + (size_t)b * S * H2;   // [t][h]
    const float* wa = wacc + b * S;
    const float* db = dis + b * S;
    const int* mb = mask + b * S;

    float acc = 0.f;
    for (int t = 0; t < S; ++t)
        acc += bf2f((unsigned short)xb[(size_t)t * H2 + h]) * wa[t] * db[t];

    float msum = 0.f;
    for (int i = h; i < S; i += 128) msum += (float)mb[i];
    #pragma unroll
    for (int off = 1; off < 64; off <<= 1) msum += __shfl_xor(msum, off);
    __shared__ float redm[2], redv[2];
    if ((h & 63) == 0) redm[h >> 6] = msum;
    __syncthreads();
    msum = redm[0] + redm[1];

    const float e = b2[h] + acc / msum;
    float val = e * Wc[h];
    #pragma unroll
    for (int off = 1; off < 64; off <<= 1) val += __shfl_xor(val, off);
    if ((h & 63) == 0) redv[h >> 6] = val;
    __syncthreads();
    if (h == 0) {
        float z = redv[0] + redv[1] + bc[0];
        out[b] = 1.f / (1.f + expf(-z));
    }
}

extern "C" void kernel_launch(void* const* d_in, const int* in_sizes, int n_in,
                              void* d_out, int out_size, void* d_ws, size_t ws_size,
                              hipStream_t stream) {
    const float* H    = (const float*)d_in[0];
    const int*   mask = (const int*)d_in[1];
    const float* W1   = (const float*)d_in[2];
    const float* b1   = (const float*)d_in[3];
    const float* W2   = (const float*)d_in[4];
    const float* b2   = (const float*)d_in[5];
    const float* Wc   = (const float*)d_in[6];
    const float* bc   = (const float*)d_in[7];
    float* out = (float*)d_out;

    const int NTOK = B * S;  // 32768

    // workspace layout (bytes)
    char* wsb = (char*)d_ws;
    short* Hb    = (short*)(wsb);                       // 25165824 el (48 MB)
    short* y1    = (short*)(wsb);                       // overlays Hb (dead by then)
    short* Lbuf  = (short*)(wsb + 50331648);            // 16777216 el (32 MB)
    short* xw1d  = (short*)(wsb + 83886080);            // 8388608 el (16 MB)
    short* xw2   = (short*)(wsb + 100663296);           // 4194304 el (8 MB), [tok][H2]
    float* rsum  = (float*)(wsb + 109051904);           // 32768 f
    float* wacc  = rsum + NTOK;                         // 32768 f (contiguous)
    float* dis   = wacc + NTOK;                         // 32768 f
    short* W1T   = (short*)(dis + NTOK);                // 196608 el
    short* W2T   = W1T + 196608;                        // 32768 el

    (void)hipMemsetAsync(rsum, 0, 2 * NTOK * sizeof(float), stream);  // rsum + wacc

    k_cast<<<2048, 256, 0, stream>>>(H, Hb, NTOK * D / 8);
    k_castT<<<768, 256, 0, stream>>>(W1, W1T, D, H1);
    k_castT<<<128, 256, 0, stream>>>(W2, W2T, H1, H2);

    // expL (symmetric, upper blocks, dbuf + XCD swizzle) + row sums
    k_logits_sym<<<640, 256, 0, stream>>>(Hb, Lbuf, rsum);

    // deg -> dis, sparse wacc
    k_prep<<<NTOK / 4, 256, 0, stream>>>(Lbuf, rsum, mask, dis, wacc);

    // xw1d[tok][h1] = dis_tok * (H @ W1)[tok][h1]  (M=H1, N=NTOK)
    k_gemm_nt<3><<<dim3(H1 / 128, NTOK / 128, 1), 256, 0, stream>>>(
        W1T, Hb, xw1d, D, D, D, H1, dis);

    // sparse aggregation + relu + bias
    k_agg<<<NTOK, 256, 0, stream>>>(Lbuf, rsum, dis, xw1d, b1, y1);

    // xw2[tok][h2] = (y1 @ W2)[tok][h2]   (M=H2, N=NTOK, K=H1)
    k_gemm_nt<0><<<dim3(H2 / 128, NTOK / 128, 1), 256, 0, stream>>>(
        W2T, y1, xw2, H1, H1, H1, H2, nullptr);

    k_final<<<B, 128, 0, stream>>>(xw2, wacc, dis, mask, b2, Wc, bc, out);
}

// Round 8
// 181.949 us; speedup vs baseline: 1.0488x; 1.0397x over previous
//
#include <hip/hip_runtime.h>
#include <hip/hip_bf16.h>
#include <math.h>

constexpr int B = 64, S = 512, D = 768, H1 = 256, H2 = 128;
constexpr float THR = 0.1f;

typedef short bf16x8 __attribute__((ext_vector_type(8)));
typedef float f32x4 __attribute__((ext_vector_type(4)));
typedef unsigned int uint_t;
typedef const __attribute__((address_space(1))) unsigned int* gptr_t;
typedef __attribute__((address_space(3))) unsigned int* lptr_t;

__device__ __forceinline__ unsigned short f2bf(float f) {
    unsigned int u = __builtin_bit_cast(unsigned int, f);
    unsigned int r = (u + 0x7FFFu + ((u >> 16) & 1u)) >> 16;
    return (unsigned short)r;
}
__device__ __forceinline__ float bf2f(unsigned short b) {
    return __builtin_bit_cast(float, (unsigned int)b << 16);
}
__device__ __forceinline__ void unpack8(const uint4& r, float* v) {
    v[0] = __builtin_bit_cast(float, r.x << 16); v[1] = __builtin_bit_cast(float, r.x & 0xFFFF0000u);
    v[2] = __builtin_bit_cast(float, r.y << 16); v[3] = __builtin_bit_cast(float, r.y & 0xFFFF0000u);
    v[4] = __builtin_bit_cast(float, r.z << 16); v[5] = __builtin_bit_cast(float, r.z & 0xFFFF0000u);
    v[6] = __builtin_bit_cast(float, r.w << 16); v[7] = __builtin_bit_cast(float, r.w & 0xFFFF0000u);
}
__device__ __forceinline__ void gl2lds16(const void* g, void* l) {
    __builtin_amdgcn_global_load_lds((gptr_t)g, (lptr_t)l, 16, 0, 0);
}

// ---------------- cast H fp32 -> bf16; also zero rsum+wacc ----------------------
__global__ __launch_bounds__(256) void k_cast(const float* __restrict__ in,
                                              short* __restrict__ out, int n8,
                                              float* __restrict__ zbuf) {
    const int id = blockIdx.x * 256 + threadIdx.x;
    if (id < 16384) ((float4*)zbuf)[id] = make_float4(0.f, 0.f, 0.f, 0.f);
    for (int i = id; i < n8; i += gridDim.x * 256) {
        float4 a = ((const float4*)in)[i * 2];
        float4 b = ((const float4*)in)[i * 2 + 1];
        uint4 o;
        o.x = (uint_t)f2bf(a.x) | ((uint_t)f2bf(a.y) << 16);
        o.y = (uint_t)f2bf(a.z) | ((uint_t)f2bf(a.w) << 16);
        o.z = (uint_t)f2bf(b.x) | ((uint_t)f2bf(b.y) << 16);
        o.w = (uint_t)f2bf(b.z) | ((uint_t)f2bf(b.w) << 16);
        ((uint4*)out)[i] = o;
    }
}

// ---------------- cast + transpose weights: in[K][N] -> out[N][K] bf16 ----------
__global__ __launch_bounds__(256) void k_castT(const float* __restrict__ in,
                                               short* __restrict__ out, int Kd, int Nd) {
    int idx = blockIdx.x * 256 + threadIdx.x;
    if (idx >= Kd * Nd) return;
    int n = idx / Kd, k = idx - n * Kd;
    out[idx] = (short)f2bf(in[(size_t)k * Nd + n]);
}

// ---------------- logits: full grid, expL + atomic row-sums ---------------------
// 1024 blocks (16 tiles x 64 batches), batch-contiguous XCD swizzle, 32KB LDS
// single buffer (5 blocks/CU LDS-cap), XOR-swizzled staging (conflict-free reads).
__global__ __launch_bounds__(256) void k_logits(const short* __restrict__ Hb_,
                                                short* __restrict__ L,
                                                float* __restrict__ rsum) {
    const int orig = blockIdx.x;
    const int wg = (orig & 7) * 128 + (orig >> 3);   // 8 XCDs x 128 = 8 batches each
    const int bz = wg >> 4;
    const int bi = (wg >> 2) & 3, bj = wg & 3;
    const short* Ab = Hb_ + (size_t)bz * S * D;
    short* Lb = L + (size_t)bz * S * S;
    float* rs = rsum + bz * S;
    const int M0 = bi * 128, N0 = bj * 128;

    __shared__ __align__(16) short As[8192];
    __shared__ __align__(16) short Bs[8192];

    const int tid = threadIdx.x, lane = tid & 63, wid = tid >> 6;
    const int wm = (wid & 1) * 64, wn = (wid >> 1) * 64;
    const int r_in = lane >> 3, kc = lane & 7;
    const int kswz = ((kc ^ r_in) << 3);   // source granule pre-swizzle (row&7==r_in)

    f32x4 zero = {0.f, 0.f, 0.f, 0.f};
    f32x4 acc[4][4];
    #pragma unroll
    for (int mi = 0; mi < 4; ++mi)
        #pragma unroll
        for (int nj = 0; nj < 4; ++nj) acc[mi][nj] = zero;

    for (int t = 0; t < 12; ++t) {
        const int kt = t * 64;
        #pragma unroll
        for (int q = 0; q < 4; ++q) {
            const int ch = wid * 4 + q;
            gl2lds16(Ab + (size_t)(M0 + ch * 8 + r_in) * D + kt + kswz, &As[ch * 512]);
        }
        #pragma unroll
        for (int q = 0; q < 4; ++q) {
            const int ch = wid * 4 + q;
            gl2lds16(Ab + (size_t)(N0 + ch * 8 + r_in) * D + kt + kswz, &Bs[ch * 512]);
        }
        __syncthreads();
        #pragma unroll
        for (int kk = 0; kk < 2; ++kk) {
            bf16x8 af[4], bfr[4];
            const int g0 = kk * 4 + (lane >> 4);   // granule index 0..7
            #pragma unroll
            for (int mi = 0; mi < 4; ++mi) {
                const int row = wm + mi * 16 + (lane & 15);
                af[mi] = *(const bf16x8*)&As[row * 64 + ((g0 ^ (row & 7)) << 3)];
            }
            #pragma unroll
            for (int nj = 0; nj < 4; ++nj) {
                const int row = wn + nj * 16 + (lane & 15);
                bfr[nj] = *(const bf16x8*)&Bs[row * 64 + ((g0 ^ (row & 7)) << 3)];
            }
            #pragma unroll
            for (int mi = 0; mi < 4; ++mi)
                #pragma unroll
                for (int nj = 0; nj < 4; ++nj)
                    acc[mi][nj] = __builtin_amdgcn_mfma_f32_16x16x32_bf16(
                        af[mi], bfr[nj], acc[mi][nj], 0, 0, 0);
        }
        __syncthreads();
    }

    // exp in place
    #pragma unroll
    for (int mi = 0; mi < 4; ++mi)
        #pragma unroll
        for (int nj = 0; nj < 4; ++nj) {
            f32x4 v = acc[mi][nj];
            acc[mi][nj][0] = __expf(v[0]);
            acc[mi][nj][1] = __expf(v[1]);
            acc[mi][nj][2] = __expf(v[2]);
            acc[mi][nj][3] = __expf(v[3]);
        }

    // store [n][m] (symmetric matrix: orientation-free)
    #pragma unroll
    for (int mi = 0; mi < 4; ++mi) {
        const int mb = wm + mi * 16 + (lane >> 4) * 4;
        #pragma unroll
        for (int nj = 0; nj < 4; ++nj) {
            const int n = wn + nj * 16 + (lane & 15);
            f32x4 v = acc[mi][nj];
            ushort4 o = make_ushort4(f2bf(v[0]), f2bf(v[1]), f2bf(v[2]), f2bf(v[3]));
            *(ushort4*)&Lb[(size_t)(N0 + n) * S + M0 + mb] = o;
        }
    }

    // col-partials: rsum[m] += sum over this tile's n (full grid covers all n)
    #pragma unroll
    for (int mi = 0; mi < 4; ++mi)
        #pragma unroll
        for (int r = 0; r < 4; ++r) {
            float s = acc[mi][0][r] + acc[mi][1][r] + acc[mi][2][r] + acc[mi][3][r];
            s += __shfl_xor(s, 1); s += __shfl_xor(s, 2);
            s += __shfl_xor(s, 4); s += __shfl_xor(s, 8);
            if ((lane & 15) == 0)
                atomicAdd(&rs[M0 + wm + mi * 16 + (lane >> 4) * 4 + r], s);
        }
}

// ---------------- prep: deg->dis, sparse wacc, CSR emit -------------------------
__global__ __launch_bounds__(256) void k_prep(const short* __restrict__ L,
                                              const float* __restrict__ rsum,
                                              const int* __restrict__ mask,
                                              float* __restrict__ dis,
                                              float* __restrict__ wacc,
                                              uint_t* __restrict__ ents,
                                              uint_t* __restrict__ cnts) {
    const int j = blockIdx.x * 4 + (threadIdx.x >> 6);  // b*S + jl
    const int lane = threadIdx.x & 63;
    const int b = j >> 9, jl = j & (S - 1);
    const size_t base = (size_t)b * S * S + (size_t)jl * S + lane * 8;
    uint4 r = *(const uint4*)(L + base);
    float v[8];
    unpack8(r, v);
    const int i0 = lane * 8;
    const float4 sa = *(const float4*)&rsum[b * S + i0];
    const float4 sb = *(const float4*)&rsum[b * S + i0 + 4];
    const float rsv[8] = {sa.x, sa.y, sa.z, sa.w, sb.x, sb.y, sb.z, sb.w};
    float a[8];
    float deg = 0.f;
    #pragma unroll
    for (int e = 0; e < 8; ++e) {
        float att = v[e] / rsv[e];   // att[i][j], i = i0+e
        if (i0 + e == jl) a[e] = (att > THR) ? att : 1.0f;
        else              a[e] = (att > THR) ? att : 0.0f;
        deg += a[e];
    }
    #pragma unroll
    for (int off = 1; off < 64; off <<= 1) deg += __shfl_xor(deg, off);
    const float d = (deg > 0.f) ? rsqrtf(deg) : 0.f;
    const float cv = d * (float)mask[j];
    if (lane == 0) dis[j] = d;
    #pragma unroll
    for (int e = 0; e < 8; ++e)
        if (a[e] != 0.f) atomicAdd(&wacc[b * S + i0 + e], cv * a[e]);

    // CSR emit, deterministic i-order via ballot ranking
    unsigned long long bl[8];
    #pragma unroll
    for (int e = 0; e < 8; ++e) bl[e] = __ballot(a[e] != 0.f);
    const unsigned long long lt = (lane == 0) ? 0ull : (~0ull >> (64 - lane));
    int pre = 0, tot = 0;
    #pragma unroll
    for (int e = 0; e < 8; ++e) {
        pre += __popcll(bl[e] & lt);
        tot += __popcll(bl[e]);
    }
    uint_t* rowents = ents + (size_t)j * S;
    int own = 0;
    #pragma unroll
    for (int e = 0; e < 8; ++e) {
        if (a[e] != 0.f) {
            rowents[pre + own] = ((uint_t)(i0 + e) << 16) | (uint_t)f2bf(a[e]);
            ++own;
        }
    }
    if (lane == 0) cnts[j] = (uint_t)tot;
}

// ---------------- sparse aggregation via CSR: y1[j][h] ---------------------------
__global__ __launch_bounds__(256) void k_agg(const uint_t* __restrict__ ents,
                                             const uint_t* __restrict__ cnts,
                                             const float* __restrict__ dis,
                                             const short* __restrict__ xw1d,
                                             const float* __restrict__ b1,
                                             short* __restrict__ y1) {
    const int j = blockIdx.x;            // b*S + jl
    const int b = j >> 9;
    const int tid = threadIdx.x;
    const int cnt = (int)cnts[j];
    __shared__ uint_t sents[S];
    for (int k = tid; k < cnt; k += 256) sents[k] = ents[(size_t)j * S + k];
    __syncthreads();
    const int h = tid;
    float acc = 0.f;
    for (int k = 0; k < cnt; ++k) {
        const uint_t p = sents[k];
        const int i = (int)(p >> 16);
        const float val = bf2f((unsigned short)(p & 0xFFFFu));
        acc += val * bf2f((unsigned short)xw1d[(size_t)(b * S + i) * H1 + h]);
    }
    const float o = fmaxf(dis[j] * acc + b1[h], 0.f);
    y1[(size_t)j * H1 + h] = (short)f2bf(o);
}

// ---------------- generic NT-GEMM, bf16 MFMA, dbuf + XOR swizzle, C [N][M] ------
// MODE 0: plain; 3: v * sN[n]
template <int MODE>
__global__ __launch_bounds__(256) void k_gemm_nt(
    const short* __restrict__ A, const short* __restrict__ Bm, short* __restrict__ C,
    int K, int lda, int ldb, int ldc,
    const float* __restrict__ sN) {
    const int M0 = blockIdx.x * 128, N0 = blockIdx.y * 128;

    __shared__ __align__(16) short As[2][8192];
    __shared__ __align__(16) short Bs[2][8192];

    const int tid = threadIdx.x, lane = tid & 63, wid = tid >> 6;
    const int wm = (wid & 1) * 64, wn = (wid >> 1) * 64;
    const int r_in = lane >> 3, kc = lane & 7;
    const int kswz = ((kc ^ r_in) << 3);

    auto stage = [&](int buf, int kt) {
        #pragma unroll
        for (int q = 0; q < 4; ++q) {
            const int ch = wid * 4 + q;
            gl2lds16(A + (size_t)(M0 + ch * 8 + r_in) * lda + kt + kswz, &As[buf][ch * 512]);
        }
        #pragma unroll
        for (int q = 0; q < 4; ++q) {
            const int ch = wid * 4 + q;
            gl2lds16(Bm + (size_t)(N0 + ch * 8 + r_in) * ldb + kt + kswz, &Bs[buf][ch * 512]);
        }
    };

    f32x4 zero = {0.f, 0.f, 0.f, 0.f};
    f32x4 acc[4][4];
    #pragma unroll
    for (int mi = 0; mi < 4; ++mi)
        #pragma unroll
        for (int nj = 0; nj < 4; ++nj) acc[mi][nj] = zero;

    const int nt = K >> 6;
    stage(0, 0);
    __syncthreads();
    int cur = 0;
    for (int t = 0; t < nt; ++t) {
        if (t + 1 < nt) stage(cur ^ 1, (t + 1) << 6);
        #pragma unroll
        for (int kk = 0; kk < 2; ++kk) {
            bf16x8 af[4], bfr[4];
            const int g0 = kk * 4 + (lane >> 4);
            #pragma unroll
            for (int mi = 0; mi < 4; ++mi) {
                const int row = wm + mi * 16 + (lane & 15);
                af[mi] = *(const bf16x8*)&As[cur][row * 64 + ((g0 ^ (row & 7)) << 3)];
            }
            #pragma unroll
            for (int nj = 0; nj < 4; ++nj) {
                const int row = wn + nj * 16 + (lane & 15);
                bfr[nj] = *(const bf16x8*)&Bs[cur][row * 64 + ((g0 ^ (row & 7)) << 3)];
            }
            #pragma unroll
            for (int mi = 0; mi < 4; ++mi)
                #pragma unroll
                for (int nj = 0; nj < 4; ++nj)
                    acc[mi][nj] = __builtin_amdgcn_mfma_f32_16x16x32_bf16(
                        af[mi], bfr[nj], acc[mi][nj], 0, 0, 0);
        }
        __syncthreads();
        cur ^= 1;
    }

    #pragma unroll
    for (int mi = 0; mi < 4; ++mi) {
        const int m = M0 + wm + mi * 16 + (lane >> 4) * 4;
        #pragma unroll
        for (int nj = 0; nj < 4; ++nj) {
            const int n = N0 + wn + nj * 16 + (lane & 15);
            f32x4 v = acc[mi][nj];
            float o0 = v[0], o1 = v[1], o2 = v[2], o3 = v[3];
            if (MODE == 3) {
                const float sn = sN[n];
                o0 *= sn; o1 *= sn; o2 *= sn; o3 *= sn;
            }
            ushort4 o = make_ushort4(f2bf(o0), f2bf(o1), f2bf(o2), f2bf(o3));
            *(ushort4*)&C[(size_t)n * ldc + m] = o;
        }
    }
}

// ---------------- final: weighted colsum of xw2[tok][H2] + head (512 thr) -------
__global__ __launch_bounds__(512) void k_final(const short* __restrict__ xw2,
                                               const float* __restrict__ wacc,
                                               const float* __restrict__ dis,
                                               const int* __restrict__ mask,
                                               const float* __restrict__ b2,
                                               const float* __restrict__ Wc,
                                               const float* __restrict__ bc,
                                               float* __restrict__ out) {
    const int b = blockIdx.x;
    const int tid = threadIdx.x;
    const int h = tid & 127, q = tid >> 7;
    const short* xb = xw2 + (size_t)b * S * H2;
    const float* wa = wacc + b * S;
    const float* db = dis + b * S;
    const int* mb = mask + b * S;

    float acc = 0.f;
    for (int t = q * 128; t < q * 128 + 128; ++t)
        acc += bf2f((unsigned short)xb[(size_t)t * H2 + h]) * wa[t] * db[t];

    __shared__ float red[4][128];
    __shared__ float redm[2], redv[2];
    red[q][h] = acc;
    __syncthreads();

    float msum = 0.f;
    if (q == 0) {
        acc = red[0][h] + red[1][h] + red[2][h] + red[3][h];
        for (int i = h; i < S; i += 128) msum += (float)mb[i];
        #pragma unroll
        for (int off = 1; off < 64; off <<= 1) msum += __shfl_xor(msum, off);
        if ((h & 63) == 0) redm[h >> 6] = msum;
    }
    __syncthreads();
    if (q == 0) {
        msum = redm[0] + redm[1];
        const float e = b2[h] + acc / msum;
        float val = e * Wc[h];
        #pragma unroll
        for (int off = 1; off < 64; off <<= 1) val += __shfl_xor(val, off);
        if ((h & 63) == 0) redv[h >> 6] = val;
    }
    __syncthreads();
    if (tid == 0) {
        float z = redv[0] + redv[1] + bc[0];
        out[b] = 1.f / (1.f + expf(-z));
    }
}

extern "C" void kernel_launch(void* const* d_in, const int* in_sizes, int n_in,
                              void* d_out, int out_size, void* d_ws, size_t ws_size,
                              hipStream_t stream) {
    const float* H    = (const float*)d_in[0];
    const int*   mask = (const int*)d_in[1];
    const float* W1   = (const float*)d_in[2];
    const float* b1   = (const float*)d_in[3];
    const float* W2   = (const float*)d_in[4];
    const float* b2   = (const float*)d_in[5];
    const float* Wc   = (const float*)d_in[6];
    const float* bc   = (const float*)d_in[7];
    float* out = (float*)d_out;

    const int NTOK = B * S;  // 32768

    // workspace layout (bytes)
    char* wsb = (char*)d_ws;
    short* Hb    = (short*)(wsb);                       // 25165824 el (48 MB)
    short* y1    = (short*)(wsb);                       // overlays Hb (dead by then)
    short* Lbuf  = (short*)(wsb + 50331648);            // 16777216 el (32 MB)
    short* xw1d  = (short*)(wsb + 83886080);            // 8388608 el (16 MB)
    short* xw2   = (short*)(wsb + 100663296);           // 4194304 el (8 MB), [tok][H2]
    float* rsum  = (float*)(wsb + 109051904);           // 32768 f
    float* wacc  = rsum + NTOK;                         // 32768 f (contiguous)
    float* dis   = wacc + NTOK;                         // 32768 f
    short* W1T   = (short*)(dis + NTOK);                // 196608 el
    short* W2T   = W1T + 196608;                        // 32768 el
    uint_t* ents = (uint_t*)(wsb + 134217728);          // 32768*512 u32 (64 MB)
    uint_t* cnts = (uint_t*)(wsb + 201326592);          // 32768 u32

    k_cast<<<2048, 256, 0, stream>>>(H, Hb, NTOK * D / 8, rsum);  // also zeroes rsum+wacc
    k_castT<<<768, 256, 0, stream>>>(W1, W1T, D, H1);
    k_castT<<<128, 256, 0, stream>>>(W2, W2T, H1, H2);

    // expL (full grid, XCD swizzle, swizzled LDS) + row sums
    k_logits<<<1024, 256, 0, stream>>>(Hb, Lbuf, rsum);

    // deg -> dis, sparse wacc, CSR
    k_prep<<<NTOK / 4, 256, 0, stream>>>(Lbuf, rsum, mask, dis, wacc, ents, cnts);

    // xw1d[tok][h1] = dis_tok * (H @ W1)[tok][h1]  (M=H1, N=NTOK)
    k_gemm_nt<3><<<dim3(H1 / 128, NTOK / 128, 1), 256, 0, stream>>>(
        W1T, Hb, xw1d, D, D, D, H1, dis);

    // sparse aggregation + relu + bias (CSR-driven)
    k_agg<<<NTOK, 256, 0, stream>>>(ents, cnts, dis, xw1d, b1, y1);

    // xw2[tok][h2] = (y1 @ W2)[tok][h2]   (M=H2, N=NTOK, K=H1)
    k_gemm_nt<0><<<dim3(H2 / 128, NTOK / 128, 1), 256, 0, stream>>>(
        W2T, y1, xw2, H1, H1, H1, H2, nullptr);

    k_final<<<B, 512, 0, stream>>>(xw2, wacc, dis, mask, b2, Wc, bc, out);
}

// Round 9
// 148.784 us; speedup vs baseline: 1.2826x; 1.2229x over previous
//
#include <hip/hip_runtime.h>
#include <hip/hip_bf16.h>
#include <math.h>

constexpr int B = 64, S = 512, D = 768, H1 = 256, H2 = 128;
constexpr float THR = 0.1f;

typedef short bf16x8 __attribute__((ext_vector_type(8)));
typedef float f32x4 __attribute__((ext_vector_type(4)));
typedef unsigned int uint_t;
typedef const __attribute__((address_space(1))) unsigned int* gptr_t;
typedef __attribute__((address_space(3))) unsigned int* lptr_t;

__device__ __forceinline__ unsigned short f2bf(float f) {
    unsigned int u = __builtin_bit_cast(unsigned int, f);
    unsigned int r = (u + 0x7FFFu + ((u >> 16) & 1u)) >> 16;
    return (unsigned short)r;
}
__device__ __forceinline__ float bf2f(unsigned short b) {
    return __builtin_bit_cast(float, (unsigned int)b << 16);
}
__device__ __forceinline__ void unpack8(const uint4& r, float* v) {
    v[0] = __builtin_bit_cast(float, r.x << 16); v[1] = __builtin_bit_cast(float, r.x & 0xFFFF0000u);
    v[2] = __builtin_bit_cast(float, r.y << 16); v[3] = __builtin_bit_cast(float, r.y & 0xFFFF0000u);
    v[4] = __builtin_bit_cast(float, r.z << 16); v[5] = __builtin_bit_cast(float, r.z & 0xFFFF0000u);
    v[6] = __builtin_bit_cast(float, r.w << 16); v[7] = __builtin_bit_cast(float, r.w & 0xFFFF0000u);
}
__device__ __forceinline__ void gl2lds16(const void* g, void* l) {
    __builtin_amdgcn_global_load_lds((gptr_t)g, (lptr_t)l, 16, 0, 0);
}

// ------- fused prologue: zero accumulators, transpose-cast W1/W2, cast H --------
__global__ __launch_bounds__(256) void k_cast(const float* __restrict__ in,
                                              short* __restrict__ out,
                                              const float* __restrict__ W1,
                                              short* __restrict__ W1T,
                                              const float* __restrict__ W2,
                                              short* __restrict__ W2T,
                                              float* __restrict__ zbuf) {
    const int id = blockIdx.x * 256 + threadIdx.x;
    if (id < 18432) ((float4*)zbuf)[id] = make_float4(0.f, 0.f, 0.f, 0.f);
    if (id < 196608) {                       // W1T[n][k] = W1[k][n]
        const int n = id / D, k = id - n * D;
        W1T[id] = (short)f2bf(W1[(size_t)k * H1 + n]);
    } else if (id < 229376) {                // W2T[n][k] = W2[k][n]
        const int i2 = id - 196608;
        const int n = i2 / H1, k = i2 - n * H1;
        W2T[i2] = (short)f2bf(W2[(size_t)k * H2 + n]);
    }
    for (int i = id; i < 3145728; i += 524288) {
        float4 a = ((const float4*)in)[i * 2];
        float4 b = ((const float4*)in)[i * 2 + 1];
        uint4 o;
        o.x = (uint_t)f2bf(a.x) | ((uint_t)f2bf(a.y) << 16);
        o.y = (uint_t)f2bf(a.z) | ((uint_t)f2bf(a.w) << 16);
        o.z = (uint_t)f2bf(b.x) | ((uint_t)f2bf(b.y) << 16);
        o.w = (uint_t)f2bf(b.z) | ((uint_t)f2bf(b.w) << 16);
        ((uint4*)out)[i] = o;
    }
}

// ---------------- logits: full grid, expL + atomic row-sums (as R8) -------------
__global__ __launch_bounds__(256) void k_logits(const short* __restrict__ Hb_,
                                                short* __restrict__ L,
                                                float* __restrict__ rsum) {
    const int orig = blockIdx.x;
    const int wg = (orig & 7) * 128 + (orig >> 3);
    const int bz = wg >> 4;
    const int bi = (wg >> 2) & 3, bj = wg & 3;
    const short* Ab = Hb_ + (size_t)bz * S * D;
    short* Lb = L + (size_t)bz * S * S;
    float* rs = rsum + bz * S;
    const int M0 = bi * 128, N0 = bj * 128;

    __shared__ __align__(16) short As[8192];
    __shared__ __align__(16) short Bs[8192];

    const int tid = threadIdx.x, lane = tid & 63, wid = tid >> 6;
    const int wm = (wid & 1) * 64, wn = (wid >> 1) * 64;
    const int r_in = lane >> 3, kc = lane & 7;
    const int kswz = ((kc ^ r_in) << 3);

    f32x4 zero = {0.f, 0.f, 0.f, 0.f};
    f32x4 acc[4][4];
    #pragma unroll
    for (int mi = 0; mi < 4; ++mi)
        #pragma unroll
        for (int nj = 0; nj < 4; ++nj) acc[mi][nj] = zero;

    for (int t = 0; t < 12; ++t) {
        const int kt = t * 64;
        #pragma unroll
        for (int q = 0; q < 4; ++q) {
            const int ch = wid * 4 + q;
            gl2lds16(Ab + (size_t)(M0 + ch * 8 + r_in) * D + kt + kswz, &As[ch * 512]);
        }
        #pragma unroll
        for (int q = 0; q < 4; ++q) {
            const int ch = wid * 4 + q;
            gl2lds16(Ab + (size_t)(N0 + ch * 8 + r_in) * D + kt + kswz, &Bs[ch * 512]);
        }
        __syncthreads();
        #pragma unroll
        for (int kk = 0; kk < 2; ++kk) {
            bf16x8 af[4], bfr[4];
            const int g0 = kk * 4 + (lane >> 4);
            #pragma unroll
            for (int mi = 0; mi < 4; ++mi) {
                const int row = wm + mi * 16 + (lane & 15);
                af[mi] = *(const bf16x8*)&As[row * 64 + ((g0 ^ (row & 7)) << 3)];
            }
            #pragma unroll
            for (int nj = 0; nj < 4; ++nj) {
                const int row = wn + nj * 16 + (lane & 15);
                bfr[nj] = *(const bf16x8*)&Bs[row * 64 + ((g0 ^ (row & 7)) << 3)];
            }
            #pragma unroll
            for (int mi = 0; mi < 4; ++mi)
                #pragma unroll
                for (int nj = 0; nj < 4; ++nj)
                    acc[mi][nj] = __builtin_amdgcn_mfma_f32_16x16x32_bf16(
                        af[mi], bfr[nj], acc[mi][nj], 0, 0, 0);
        }
        __syncthreads();
    }

    #pragma unroll
    for (int mi = 0; mi < 4; ++mi)
        #pragma unroll
        for (int nj = 0; nj < 4; ++nj) {
            f32x4 v = acc[mi][nj];
            acc[mi][nj][0] = __expf(v[0]);
            acc[mi][nj][1] = __expf(v[1]);
            acc[mi][nj][2] = __expf(v[2]);
            acc[mi][nj][3] = __expf(v[3]);
        }

    #pragma unroll
    for (int mi = 0; mi < 4; ++mi) {
        const int mb = wm + mi * 16 + (lane >> 4) * 4;
        #pragma unroll
        for (int nj = 0; nj < 4; ++nj) {
            const int n = wn + nj * 16 + (lane & 15);
            f32x4 v = acc[mi][nj];
            ushort4 o = make_ushort4(f2bf(v[0]), f2bf(v[1]), f2bf(v[2]), f2bf(v[3]));
            *(ushort4*)&Lb[(size_t)(N0 + n) * S + M0 + mb] = o;
        }
    }

    #pragma unroll
    for (int mi = 0; mi < 4; ++mi)
        #pragma unroll
        for (int r = 0; r < 4; ++r) {
            float s = acc[mi][0][r] + acc[mi][1][r] + acc[mi][2][r] + acc[mi][3][r];
            s += __shfl_xor(s, 1); s += __shfl_xor(s, 2);
            s += __shfl_xor(s, 4); s += __shfl_xor(s, 8);
            if ((lane & 15) == 0)
                atomicAdd(&rs[M0 + wm + mi * 16 + (lane >> 4) * 4 + r], s);
        }
}

// ---------------- prep: deg->dis, sparse wacc, CSR emit (as R8) -----------------
__global__ __launch_bounds__(256) void k_prep(const short* __restrict__ L,
                                              const float* __restrict__ rsum,
                                              const int* __restrict__ mask,
                                              float* __restrict__ dis,
                                              float* __restrict__ wacc,
                                              uint_t* __restrict__ ents,
                                              uint_t* __restrict__ cnts) {
    const int j = blockIdx.x * 4 + (threadIdx.x >> 6);
    const int lane = threadIdx.x & 63;
    const int b = j >> 9, jl = j & (S - 1);
    const size_t base = (size_t)b * S * S + (size_t)jl * S + lane * 8;
    uint4 r = *(const uint4*)(L + base);
    float v[8];
    unpack8(r, v);
    const int i0 = lane * 8;
    const float4 sa = *(const float4*)&rsum[b * S + i0];
    const float4 sb = *(const float4*)&rsum[b * S + i0 + 4];
    const float rsv[8] = {sa.x, sa.y, sa.z, sa.w, sb.x, sb.y, sb.z, sb.w};
    float a[8];
    float deg = 0.f;
    #pragma unroll
    for (int e = 0; e < 8; ++e) {
        float att = v[e] / rsv[e];
        if (i0 + e == jl) a[e] = (att > THR) ? att : 1.0f;
        else              a[e] = (att > THR) ? att : 0.0f;
        deg += a[e];
    }
    #pragma unroll
    for (int off = 1; off < 64; off <<= 1) deg += __shfl_xor(deg, off);
    const float d = (deg > 0.f) ? rsqrtf(deg) : 0.f;
    const float cv = d * (float)mask[j];
    if (lane == 0) dis[j] = d;
    #pragma unroll
    for (int e = 0; e < 8; ++e)
        if (a[e] != 0.f) atomicAdd(&wacc[b * S + i0 + e], cv * a[e]);

    unsigned long long bl[8];
    #pragma unroll
    for (int e = 0; e < 8; ++e) bl[e] = __ballot(a[e] != 0.f);
    const unsigned long long lt = (lane == 0) ? 0ull : (~0ull >> (64 - lane));
    int pre = 0, tot = 0;
    #pragma unroll
    for (int e = 0; e < 8; ++e) {
        pre += __popcll(bl[e] & lt);
        tot += __popcll(bl[e]);
    }
    uint_t* rowents = ents + (size_t)j * S;
    int own = 0;
    #pragma unroll
    for (int e = 0; e < 8; ++e) {
        if (a[e] != 0.f) {
            rowents[pre + own] = ((uint_t)(i0 + e) << 16) | (uint_t)f2bf(a[e]);
            ++own;
        }
    }
    if (lane == 0) cnts[j] = (uint_t)tot;
}

// ---------------- sparse aggregation via CSR: y1[j][h] (as R8) -------------------
__global__ __launch_bounds__(256) void k_agg(const uint_t* __restrict__ ents,
                                             const uint_t* __restrict__ cnts,
                                             const float* __restrict__ dis,
                                             const short* __restrict__ xw1d,
                                             const float* __restrict__ b1,
                                             short* __restrict__ y1) {
    const int j = blockIdx.x;
    const int b = j >> 9;
    const int tid = threadIdx.x;
    const int cnt = (int)cnts[j];
    __shared__ uint_t sents[S];
    for (int k = tid; k < cnt; k += 256) sents[k] = ents[(size_t)j * S + k];
    __syncthreads();
    const int h = tid;
    float acc = 0.f;
    for (int k = 0; k < cnt; ++k) {
        const uint_t p = sents[k];
        const int i = (int)(p >> 16);
        const float val = bf2f((unsigned short)(p & 0xFFFFu));
        acc += val * bf2f((unsigned short)xw1d[(size_t)(b * S + i) * H1 + h]);
    }
    const float o = fmaxf(dis[j] * acc + b1[h], 0.f);
    y1[(size_t)j * H1 + h] = (short)f2bf(o);
}

// ------- narrow-tile NT-GEMM: 128 x TN, single-buffer, XOR swizzle --------------
// MODE 3: C[n][m] = v * sN[n].  MODE 4: no C store; atomicAdd emb partials
// (v * sN[n]*sN2[n] reduced over tokens).
template <int MODE, int TN, int GX>
__global__ __launch_bounds__(256) void k_gemm(
    const short* __restrict__ A, const short* __restrict__ Bm, short* __restrict__ C,
    int K, int lda, int ldb, int ldc,
    const float* __restrict__ sN, const float* __restrict__ sN2,
    float* __restrict__ embp) {
    constexpr int NJ = TN / 32;      // B frags per wave; also B chunks per wave
    const int nwg = gridDim.x;
    const int orig = blockIdx.x;
    const int wg = (orig & 7) * (nwg >> 3) + (orig >> 3);   // XCD-contiguous chunks
    const int bx = wg % GX, by = wg / GX;
    const int M0 = bx * 128, N0 = by * TN;

    __shared__ __align__(16) short As[128 * 64];
    __shared__ __align__(16) short Bs[TN * 64];

    const int tid = threadIdx.x, lane = tid & 63, wid = tid >> 6;
    const int wm = (wid & 1) * 64, wn = (wid >> 1) * (TN / 2);
    const int r_in = lane >> 3, kc = lane & 7;
    const int kswz = ((kc ^ r_in) << 3);

    f32x4 zero = {0.f, 0.f, 0.f, 0.f};
    f32x4 acc[4][NJ];
    #pragma unroll
    for (int mi = 0; mi < 4; ++mi)
        #pragma unroll
        for (int nj = 0; nj < NJ; ++nj) acc[mi][nj] = zero;

    const int nt = K >> 6;
    for (int t = 0; t < nt; ++t) {
        const int kt = t << 6;
        #pragma unroll
        for (int q = 0; q < 4; ++q) {
            const int ch = wid * 4 + q;
            gl2lds16(A + (size_t)(M0 + ch * 8 + r_in) * lda + kt + kswz, &As[ch * 512]);
        }
        #pragma unroll
        for (int q = 0; q < NJ; ++q) {
            const int ch = wid * NJ + q;
            gl2lds16(Bm + (size_t)(N0 + ch * 8 + r_in) * ldb + kt + kswz, &Bs[ch * 512]);
        }
        __syncthreads();
        #pragma unroll
        for (int kk = 0; kk < 2; ++kk) {
            bf16x8 af[4], bfr[NJ];
            const int g0 = kk * 4 + (lane >> 4);
            #pragma unroll
            for (int mi = 0; mi < 4; ++mi) {
                const int row = wm + mi * 16 + (lane & 15);
                af[mi] = *(const bf16x8*)&As[row * 64 + ((g0 ^ (row & 7)) << 3)];
            }
            #pragma unroll
            for (int nj = 0; nj < NJ; ++nj) {
                const int row = wn + nj * 16 + (lane & 15);
                bfr[nj] = *(const bf16x8*)&Bs[row * 64 + ((g0 ^ (row & 7)) << 3)];
            }
            #pragma unroll
            for (int mi = 0; mi < 4; ++mi)
                #pragma unroll
                for (int nj = 0; nj < NJ; ++nj)
                    acc[mi][nj] = __builtin_amdgcn_mfma_f32_16x16x32_bf16(
                        af[mi], bfr[nj], acc[mi][nj], 0, 0, 0);
        }
        __syncthreads();
    }

    if (MODE == 3) {
        #pragma unroll
        for (int mi = 0; mi < 4; ++mi) {
            const int m = M0 + wm + mi * 16 + (lane >> 4) * 4;
            #pragma unroll
            for (int nj = 0; nj < NJ; ++nj) {
                const int n = N0 + wn + nj * 16 + (lane & 15);
                f32x4 v = acc[mi][nj];
                const float sn = sN[n];
                ushort4 o = make_ushort4(f2bf(v[0] * sn), f2bf(v[1] * sn),
                                         f2bf(v[2] * sn), f2bf(v[3] * sn));
                *(ushort4*)&C[(size_t)n * ldc + m] = o;
            }
        }
    } else {  // MODE 4: emb partial reduction
        const int bb = N0 >> 9;
        float wv[NJ];
        #pragma unroll
        for (int nj = 0; nj < NJ; ++nj) {
            const int gn = N0 + wn + nj * 16 + (lane & 15);
            wv[nj] = sN[gn] * sN2[gn];
        }
        #pragma unroll
        for (int mi = 0; mi < 4; ++mi)
            #pragma unroll
            for (int r = 0; r < 4; ++r) {
                float s = 0.f;
                #pragma unroll
                for (int nj = 0; nj < NJ; ++nj) s += acc[mi][nj][r] * wv[nj];
                s += __shfl_xor(s, 1); s += __shfl_xor(s, 2);
                s += __shfl_xor(s, 4); s += __shfl_xor(s, 8);
                if ((lane & 15) == 0) {
                    const int h = M0 + wm + mi * 16 + (lane >> 4) * 4 + r;
                    atomicAdd(&embp[bb * H2 + h], s);
                }
            }
    }
}

// ---------------- final: head from emb[64][128] ---------------------------------
__global__ __launch_bounds__(128) void k_final(const float* __restrict__ emb,
                                               const int* __restrict__ mask,
                                               const float* __restrict__ b2,
                                               const float* __restrict__ Wc,
                                               const float* __restrict__ bc,
                                               float* __restrict__ out) {
    const int b = blockIdx.x;
    const int h = threadIdx.x;
    const int* mb = mask + b * S;

    float msum = 0.f;
    for (int i = h; i < S; i += 128) msum += (float)mb[i];
    #pragma unroll
    for (int off = 1; off < 64; off <<= 1) msum += __shfl_xor(msum, off);
    __shared__ float redm[2], redv[2];
    if ((h & 63) == 0) redm[h >> 6] = msum;
    __syncthreads();
    msum = redm[0] + redm[1];

    const float e = b2[h] + emb[b * H2 + h] / msum;
    float val = e * Wc[h];
    #pragma unroll
    for (int off = 1; off < 64; off <<= 1) val += __shfl_xor(val, off);
    if ((h & 63) == 0) redv[h >> 6] = val;
    __syncthreads();
    if (h == 0) {
        float z = redv[0] + redv[1] + bc[0];
        out[b] = 1.f / (1.f + expf(-z));
    }
}

extern "C" void kernel_launch(void* const* d_in, const int* in_sizes, int n_in,
                              void* d_out, int out_size, void* d_ws, size_t ws_size,
                              hipStream_t stream) {
    const float* H    = (const float*)d_in[0];
    const int*   mask = (const int*)d_in[1];
    const float* W1   = (const float*)d_in[2];
    const float* b1   = (const float*)d_in[3];
    const float* W2   = (const float*)d_in[4];
    const float* b2   = (const float*)d_in[5];
    const float* Wc   = (const float*)d_in[6];
    const float* bc   = (const float*)d_in[7];
    float* out = (float*)d_out;

    const int NTOK = B * S;  // 32768

    // workspace layout (bytes)
    char* wsb = (char*)d_ws;
    short* Hb    = (short*)(wsb);                       // 48 MB
    short* y1    = (short*)(wsb);                       // overlays Hb (dead by then)
    short* Lbuf  = (short*)(wsb + 50331648);            // 32 MB
    short* xw1d  = (short*)(wsb + 83886080);            // 16 MB, [tok][H1]
    float* rsum  = (float*)(wsb + 109051904);           // 32768 f
    float* wacc  = rsum + NTOK;                         // 32768 f
    float* emb   = wacc + NTOK;                         // 8192 f  (zeroed with rsum/wacc)
    float* dis   = emb + 8192;                          // 32768 f
    short* W1T   = (short*)(dis + NTOK);                // 196608 el
    short* W2T   = W1T + 196608;                        // 32768 el
    uint_t* ents = (uint_t*)(wsb + 134217728);          // 64 MB
    uint_t* cnts = (uint_t*)(wsb + 201326592);          // 32768 u32

    // prologue: zero rsum+wacc+emb, cast weights (transposed), cast H
    k_cast<<<2048, 256, 0, stream>>>(H, Hb, W1, W1T, W2, W2T, rsum);

    // expL (full grid, XCD swizzle, swizzled LDS) + row sums
    k_logits<<<1024, 256, 0, stream>>>(Hb, Lbuf, rsum);

    // deg -> dis, sparse wacc, CSR
    k_prep<<<NTOK / 4, 256, 0, stream>>>(Lbuf, rsum, mask, dis, wacc, ents, cnts);

    // xw1d[tok][h1] = dis_tok * (H @ W1)[tok][h1]   (M=H1=256 via GX=2, N=NTOK, TN=64)
    k_gemm<3, 64, 2><<<1024, 256, 0, stream>>>(
        W1T, Hb, xw1d, D, D, D, H1, dis, nullptr, nullptr);

    // sparse aggregation + relu + bias (CSR-driven)
    k_agg<<<NTOK, 256, 0, stream>>>(ents, cnts, dis, xw1d, b1, y1);

    // emb[b][h2] += sum_t (y1 @ W2)[t][h2] * wacc[t]*dis[t]   (M=H2=128, TN=64)
    k_gemm<4, 64, 1><<<512, 256, 0, stream>>>(
        W2T, y1, nullptr, H1, H1, H1, 0, wacc, dis, emb);

    k_final<<<B, 128, 0, stream>>>(emb, mask, b2, Wc, bc, out);
}

// Round 11
// 142.723 us; speedup vs baseline: 1.3371x; 1.0425x over previous
//
#include <hip/hip_runtime.h>
#include <hip/hip_bf16.h>
#include <math.h>

constexpr int B = 64, S = 512, D = 768, H1 = 256, H2 = 128;
constexpr float THR = 0.1f;

typedef short bf16x8 __attribute__((ext_vector_type(8)));
typedef float f32x4 __attribute__((ext_vector_type(4)));
typedef unsigned int uint_t;
typedef const __attribute__((address_space(1))) unsigned int* gptr_t;
typedef __attribute__((address_space(3))) unsigned int* lptr_t;

__device__ __forceinline__ unsigned short f2bf(float f) {
    unsigned int u = __builtin_bit_cast(unsigned int, f);
    unsigned int r = (u + 0x7FFFu + ((u >> 16) & 1u)) >> 16;
    return (unsigned short)r;
}
__device__ __forceinline__ float bf2f(unsigned short b) {
    return __builtin_bit_cast(float, (unsigned int)b << 16);
}
// fp8 e4m3fn encode (input guaranteed positive, in normal range [2^-6, 448))
__device__ __forceinline__ unsigned char f2fp8(float f) {
    uint_t u = __builtin_bit_cast(uint_t, f);
    u += 0x7FFFFu + ((u >> 20) & 1u);      // RNE to 3-bit mantissa
    return (unsigned char)((((u >> 23) - 120u) << 3) | ((u >> 20) & 7u));
}
__device__ __forceinline__ float fp82f(unsigned char q) {
    uint_t e = (q >> 3) & 0xFu, m = q & 7u;
    if (e == 0) return (float)m * 0.001953125f;   // denormal: m * 2^-9
    return __builtin_bit_cast(float, ((e + 120u) << 23) | (m << 20));
}
__device__ __forceinline__ void gl2lds16(const void* g, void* l) {
    __builtin_amdgcn_global_load_lds((gptr_t)g, (lptr_t)l, 16, 0, 0);
}

// ------- fused prologue: zero accumulators, transpose-cast W1/W2, cast H --------
__global__ __launch_bounds__(256) void k_cast(const float* __restrict__ in,
                                              short* __restrict__ out,
                                              const float* __restrict__ W1,
                                              short* __restrict__ W1T,
                                              const float* __restrict__ W2,
                                              short* __restrict__ W2T,
                                              float* __restrict__ zbuf) {
    const int id = blockIdx.x * 256 + threadIdx.x;
    if (id < 18432) ((float4*)zbuf)[id] = make_float4(0.f, 0.f, 0.f, 0.f);
    if (id < 196608) {                       // W1T[n][k] = W1[k][n]
        const int n = id / D, k = id - n * D;
        W1T[id] = (short)f2bf(W1[(size_t)k * H1 + n]);
    } else if (id < 229376) {                // W2T[n][k] = W2[k][n]
        const int i2 = id - 196608;
        const int n = i2 / H1, k = i2 - n * H1;
        W2T[i2] = (short)f2bf(W2[(size_t)k * H2 + n]);
    }
    for (int i = id; i < 3145728; i += 524288) {
        float4 a = ((const float4*)in)[i * 2];
        float4 b = ((const float4*)in)[i * 2 + 1];
        uint4 o;
        o.x = (uint_t)f2bf(a.x) | ((uint_t)f2bf(a.y) << 16);
        o.y = (uint_t)f2bf(a.z) | ((uint_t)f2bf(a.w) << 16);
        o.z = (uint_t)f2bf(b.x) | ((uint_t)f2bf(b.y) << 16);
        o.w = (uint_t)f2bf(b.z) | ((uint_t)f2bf(b.w) << 16);
        ((uint4*)out)[i] = o;
    }
}

// ---------------- logits: expL (fp8) + atomic f32 row-sums ----------------------
__global__ __launch_bounds__(256) void k_logits(const short* __restrict__ Hb_,
                                                unsigned char* __restrict__ L8,
                                                float* __restrict__ rsum) {
    const int orig = blockIdx.x;
    const int wg = (orig & 7) * 128 + (orig >> 3);
    const int bz = wg >> 4;
    const int bi = (wg >> 2) & 3, bj = wg & 3;
    const short* Ab = Hb_ + (size_t)bz * S * D;
    unsigned char* Lb = L8 + (size_t)bz * S * S;
    float* rs = rsum + bz * S;
    const int M0 = bi * 128, N0 = bj * 128;

    __shared__ __align__(16) short As[8192];
    __shared__ __align__(16) short Bs[8192];

    const int tid = threadIdx.x, lane = tid & 63, wid = tid >> 6;
    const int wm = (wid & 1) * 64, wn = (wid >> 1) * 64;
    const int r_in = lane >> 3, kc = lane & 7;
    const int kswz = ((kc ^ r_in) << 3);

    f32x4 zero = {0.f, 0.f, 0.f, 0.f};
    f32x4 acc[4][4];
    #pragma unroll
    for (int mi = 0; mi < 4; ++mi)
        #pragma unroll
        for (int nj = 0; nj < 4; ++nj) acc[mi][nj] = zero;

    for (int t = 0; t < 12; ++t) {
        const int kt = t * 64;
        #pragma unroll
        for (int q = 0; q < 4; ++q) {
            const int ch = wid * 4 + q;
            gl2lds16(Ab + (size_t)(M0 + ch * 8 + r_in) * D + kt + kswz, &As[ch * 512]);
        }
        #pragma unroll
        for (int q = 0; q < 4; ++q) {
            const int ch = wid * 4 + q;
            gl2lds16(Ab + (size_t)(N0 + ch * 8 + r_in) * D + kt + kswz, &Bs[ch * 512]);
        }
        __syncthreads();
        #pragma unroll
        for (int kk = 0; kk < 2; ++kk) {
            bf16x8 af[4], bfr[4];
            const int g0 = kk * 4 + (lane >> 4);
            #pragma unroll
            for (int mi = 0; mi < 4; ++mi) {
                const int row = wm + mi * 16 + (lane & 15);
                af[mi] = *(const bf16x8*)&As[row * 64 + ((g0 ^ (row & 7)) << 3)];
            }
            #pragma unroll
            for (int nj = 0; nj < 4; ++nj) {
                const int row = wn + nj * 16 + (lane & 15);
                bfr[nj] = *(const bf16x8*)&Bs[row * 64 + ((g0 ^ (row & 7)) << 3)];
            }
            #pragma unroll
            for (int mi = 0; mi < 4; ++mi)
                #pragma unroll
                for (int nj = 0; nj < 4; ++nj)
                    acc[mi][nj] = __builtin_amdgcn_mfma_f32_16x16x32_bf16(
                        af[mi], bfr[nj], acc[mi][nj], 0, 0, 0);
        }
        __syncthreads();
    }

    #pragma unroll
    for (int mi = 0; mi < 4; ++mi)
        #pragma unroll
        for (int nj = 0; nj < 4; ++nj) {
            f32x4 v = acc[mi][nj];
            acc[mi][nj][0] = __expf(v[0]);
            acc[mi][nj][1] = __expf(v[1]);
            acc[mi][nj][2] = __expf(v[2]);
            acc[mi][nj][3] = __expf(v[3]);
        }

    #pragma unroll
    for (int mi = 0; mi < 4; ++mi) {
        const int mb = wm + mi * 16 + (lane >> 4) * 4;
        #pragma unroll
        for (int nj = 0; nj < 4; ++nj) {
            const int n = wn + nj * 16 + (lane & 15);
            f32x4 v = acc[mi][nj];
            uchar4 o;
            o.x = f2fp8(v[0]); o.y = f2fp8(v[1]);
            o.z = f2fp8(v[2]); o.w = f2fp8(v[3]);
            *(uchar4*)&Lb[(size_t)(N0 + n) * S + M0 + mb] = o;
        }
    }

    #pragma unroll
    for (int mi = 0; mi < 4; ++mi)
        #pragma unroll
        for (int r = 0; r < 4; ++r) {
            float s = acc[mi][0][r] + acc[mi][1][r] + acc[mi][2][r] + acc[mi][3][r];
            s += __shfl_xor(s, 1); s += __shfl_xor(s, 2);
            s += __shfl_xor(s, 4); s += __shfl_xor(s, 8);
            if ((lane & 15) == 0)
                atomicAdd(&rs[M0 + wm + mi * 16 + (lane >> 4) * 4 + r], s);
        }
}

// ------- fused: prep (8/9 of blocks) + xw1 NT-GEMM (1/9 of blocks) --------------
// prep: deg->dis, sparse wacc, CSR emit from fp8 expL.
// gemm: xw1[tok][h1] = (H@W1)[tok][h1] UNSCALED (no dependency on prep output —
// dis is applied per-entry in k_agg, which runs after this kernel completes).
__global__ __launch_bounds__(256) void k_prep_gemm(
    const unsigned char* __restrict__ L8, const float* __restrict__ rsum,
    const int* __restrict__ mask, float* __restrict__ dis,
    float* __restrict__ wacc, uint_t* __restrict__ ents, uint_t* __restrict__ cnts,
    const short* __restrict__ W1T, const short* __restrict__ Hb,
    short* __restrict__ xw1) {
    __shared__ __align__(16) short As[128 * 64];   // used by gemm branch only
    __shared__ __align__(16) short Bs[64 * 64];

    const int blk = blockIdx.x;
    const int r9 = blk % 9;
    const int tid = threadIdx.x, lane = tid & 63, wid = tid >> 6;

    if (r9 != 8) {
        // ---------------- prep path ----------------
        const int p = (blk / 9) * 8 + r9;            // 0..8191
        const int j = p * 4 + (tid >> 6);            // b*S + jl
        const int b = j >> 9, jl = j & (S - 1);
        const size_t base = (size_t)b * S * S + (size_t)jl * S + lane * 8;
        const uint2 r = *(const uint2*)(L8 + base);
        const int i0 = lane * 8;
        const float4 sa = *(const float4*)&rsum[b * S + i0];
        const float4 sb = *(const float4*)&rsum[b * S + i0 + 4];
        const float rsv[8] = {sa.x, sa.y, sa.z, sa.w, sb.x, sb.y, sb.z, sb.w};
        float a[8];
        float deg = 0.f;
        #pragma unroll
        for (int e = 0; e < 8; ++e) {
            const unsigned char q = (e < 4) ? (unsigned char)(r.x >> (e * 8))
                                            : (unsigned char)(r.y >> ((e - 4) * 8));
            float att = fp82f(q) / rsv[e];           // att[i][j], i = i0+e
            if (i0 + e == jl) a[e] = (att > THR) ? att : 1.0f;
            else              a[e] = (att > THR) ? att : 0.0f;
            deg += a[e];
        }
        #pragma unroll
        for (int off = 1; off < 64; off <<= 1) deg += __shfl_xor(deg, off);
        const float d = (deg > 0.f) ? rsqrtf(deg) : 0.f;
        const float cv = d * (float)mask[j];
        if (lane == 0) dis[j] = d;
        #pragma unroll
        for (int e = 0; e < 8; ++e)
            if (a[e] != 0.f) atomicAdd(&wacc[b * S + i0 + e], cv * a[e]);

        unsigned long long bl[8];
        #pragma unroll
        for (int e = 0; e < 8; ++e) bl[e] = __ballot(a[e] != 0.f);
        const unsigned long long lt = (lane == 0) ? 0ull : (~0ull >> (64 - lane));
        int pre = 0, tot = 0;
        #pragma unroll
        for (int e = 0; e < 8; ++e) {
            pre += __popcll(bl[e] & lt);
            tot += __popcll(bl[e]);
        }
        uint_t* rowents = ents + (size_t)j * S;
        int own = 0;
        #pragma unroll
        for (int e = 0; e < 8; ++e) {
            if (a[e] != 0.f) {
                rowents[pre + own] = ((uint_t)(i0 + e) << 16) | (uint_t)f2bf(a[e]);
                ++own;
            }
        }
        if (lane == 0) cnts[j] = (uint_t)tot;
        return;
    }

    // ---------------- gemm path (xw1, unscaled) ----------------
    const int orig = blk / 9;                        // 0..1023
    const int wg = (orig & 7) * 128 + (orig >> 3);   // XCD-contiguous chunks
    const int bx = wg & 1, by = wg >> 1;
    const int M0 = bx * 128, N0 = by * 64;

    const int wm = (wid & 1) * 64, wn = (wid >> 1) * 32;
    const int r_in = lane >> 3, kc = lane & 7;
    const int kswz = ((kc ^ r_in) << 3);

    f32x4 zero = {0.f, 0.f, 0.f, 0.f};
    f32x4 acc[4][2];
    #pragma unroll
    for (int mi = 0; mi < 4; ++mi) {
        acc[mi][0] = zero; acc[mi][1] = zero;
    }

    for (int t = 0; t < 12; ++t) {
        const int kt = t << 6;
        #pragma unroll
        for (int q = 0; q < 4; ++q) {
            const int ch = wid * 4 + q;
            gl2lds16(W1T + (size_t)(M0 + ch * 8 + r_in) * D + kt + kswz, &As[ch * 512]);
        }
        #pragma unroll
        for (int q = 0; q < 2; ++q) {
            const int ch = wid * 2 + q;
            gl2lds16(Hb + (size_t)(N0 + ch * 8 + r_in) * D + kt + kswz, &Bs[ch * 512]);
        }
        __syncthreads();
        #pragma unroll
        for (int kk = 0; kk < 2; ++kk) {
            bf16x8 af[4], bfr[2];
            const int g0 = kk * 4 + (lane >> 4);
            #pragma unroll
            for (int mi = 0; mi < 4; ++mi) {
                const int row = wm + mi * 16 + (lane & 15);
                af[mi] = *(const bf16x8*)&As[row * 64 + ((g0 ^ (row & 7)) << 3)];
            }
            #pragma unroll
            for (int nj = 0; nj < 2; ++nj) {
                const int row = wn + nj * 16 + (lane & 15);
                bfr[nj] = *(const bf16x8*)&Bs[row * 64 + ((g0 ^ (row & 7)) << 3)];
            }
            #pragma unroll
            for (int mi = 0; mi < 4; ++mi)
                #pragma unroll
                for (int nj = 0; nj < 2; ++nj)
                    acc[mi][nj] = __builtin_amdgcn_mfma_f32_16x16x32_bf16(
                        af[mi], bfr[nj], acc[mi][nj], 0, 0, 0);
        }
        __syncthreads();
    }

    #pragma unroll
    for (int mi = 0; mi < 4; ++mi) {
        const int m = M0 + wm + mi * 16 + (lane >> 4) * 4;
        #pragma unroll
        for (int nj = 0; nj < 2; ++nj) {
            const int n = N0 + wn + nj * 16 + (lane & 15);
            f32x4 v = acc[mi][nj];
            ushort4 o = make_ushort4(f2bf(v[0]), f2bf(v[1]), f2bf(v[2]), f2bf(v[3]));
            *(ushort4*)&xw1[(size_t)n * H1 + m] = o;
        }
    }
}

// ---------------- sparse aggregation via CSR: y1[j][h], 8 rows per block --------
// dis_i applied per entry here (xw1 is unscaled).
__global__ __launch_bounds__(256) void k_agg(const uint_t* __restrict__ ents,
                                             const uint_t* __restrict__ cnts,
                                             const float* __restrict__ dis,
                                             const short* __restrict__ xw1,
                                             const float* __restrict__ b1,
                                             short* __restrict__ y1) {
    const int tid = threadIdx.x;
    const int h = tid;
    const float bias = b1[h];
    __shared__ uint_t sents[S];
    for (int jj = 0; jj < 8; ++jj) {
        const int j = blockIdx.x * 8 + jj;
        const int b = j >> 9;
        const int cnt = (int)cnts[j];
        for (int k = tid; k < cnt; k += 256) sents[k] = ents[(size_t)j * S + k];
        __syncthreads();
        float acc = 0.f;
        for (int k = 0; k < cnt; ++k) {
            const uint_t p = sents[k];
            const int i = (int)(p >> 16);
            const float val = bf2f((unsigned short)(p & 0xFFFFu)) * dis[b * S + i];
            acc += val * bf2f((unsigned short)xw1[(size_t)(b * S + i) * H1 + h]);
        }
        const float o = fmaxf(dis[j] * acc + bias, 0.f);
        y1[(size_t)j * H1 + h] = (short)f2bf(o);
        __syncthreads();
    }
}

// ------- xw2 NT-GEMM with fused emb reduction (128 x 64 tile) -------------------
__global__ __launch_bounds__(256) void k_gemm_emb(
    const short* __restrict__ W2T, const short* __restrict__ y1,
    const float* __restrict__ wacc, const float* __restrict__ dis,
    float* __restrict__ embp) {
    const int orig = blockIdx.x;
    const int wg = (orig & 7) * 64 + (orig >> 3);
    const int N0 = wg * 64;          // token tile; M0 = 0 (H2=128 single M tile)

    __shared__ __align__(16) short As[128 * 64];
    __shared__ __align__(16) short Bs[64 * 64];

    const int tid = threadIdx.x, lane = tid & 63, wid = tid >> 6;
    const int wm = (wid & 1) * 64, wn = (wid >> 1) * 32;
    const int r_in = lane >> 3, kc = lane & 7;
    const int kswz = ((kc ^ r_in) << 3);

    f32x4 zero = {0.f, 0.f, 0.f, 0.f};
    f32x4 acc[4][2];
    #pragma unroll
    for (int mi = 0; mi < 4; ++mi) {
        acc[mi][0] = zero; acc[mi][1] = zero;
    }

    for (int t = 0; t < 4; ++t) {
        const int kt = t << 6;
        #pragma unroll
        for (int q = 0; q < 4; ++q) {
            const int ch = wid * 4 + q;
            gl2lds16(W2T + (size_t)(ch * 8 + r_in) * H1 + kt + kswz, &As[ch * 512]);
        }
        #pragma unroll
        for (int q = 0; q < 2; ++q) {
            const int ch = wid * 2 + q;
            gl2lds16(y1 + (size_t)(N0 + ch * 8 + r_in) * H1 + kt + kswz, &Bs[ch * 512]);
        }
        __syncthreads();
        #pragma unroll
        for (int kk = 0; kk < 2; ++kk) {
            bf16x8 af[4], bfr[2];
            const int g0 = kk * 4 + (lane >> 4);
            #pragma unroll
            for (int mi = 0; mi < 4; ++mi) {
                const int row = wm + mi * 16 + (lane & 15);
                af[mi] = *(const bf16x8*)&As[row * 64 + ((g0 ^ (row & 7)) << 3)];
            }
            #pragma unroll
            for (int nj = 0; nj < 2; ++nj) {
                const int row = wn + nj * 16 + (lane & 15);
                bfr[nj] = *(const bf16x8*)&Bs[row * 64 + ((g0 ^ (row & 7)) << 3)];
            }
            #pragma unroll
            for (int mi = 0; mi < 4; ++mi)
                #pragma unroll
                for (int nj = 0; nj < 2; ++nj)
                    acc[mi][nj] = __builtin_amdgcn_mfma_f32_16x16x32_bf16(
                        af[mi], bfr[nj], acc[mi][nj], 0, 0, 0);
        }
        __syncthreads();
    }

    const int bb = N0 >> 9;
    float wv[2];
    #pragma unroll
    for (int nj = 0; nj < 2; ++nj) {
        const int gn = N0 + wn + nj * 16 + (lane & 15);
        wv[nj] = wacc[gn] * dis[gn];
    }
    #pragma unroll
    for (int mi = 0; mi < 4; ++mi)
        #pragma unroll
        for (int r = 0; r < 4; ++r) {
            float s = acc[mi][0][r] * wv[0] + acc[mi][1][r] * wv[1];
            s += __shfl_xor(s, 1); s += __shfl_xor(s, 2);
            s += __shfl_xor(s, 4); s += __shfl_xor(s, 8);
            if ((lane & 15) == 0) {
                const int h = wm + mi * 16 + (lane >> 4) * 4 + r;
                atomicAdd(&embp[bb * H2 + h], s);
            }
        }
}

// ---------------- final: head from emb[64][128] ---------------------------------
__global__ __launch_bounds__(128) void k_final(const float* __restrict__ emb,
                                               const int* __restrict__ mask,
                                               const float* __restrict__ b2,
                                               const float* __restrict__ Wc,
                                               const float* __restrict__ bc,
                                               float* __restrict__ out) {
    const int b = blockIdx.x;
    const int h = threadIdx.x;
    const int* mb = mask + b * S;

    float msum = 0.f;
    for (int i = h; i < S; i += 128) msum += (float)mb[i];
    #pragma unroll
    for (int off = 1; off < 64; off <<= 1) msum += __shfl_xor(msum, off);
    __shared__ float redm[2], redv[2];
    if ((h & 63) == 0) redm[h >> 6] = msum;
    __syncthreads();
    msum = redm[0] + redm[1];

    const float e = b2[h] + emb[b * H2 + h] / msum;
    float val = e * Wc[h];
    #pragma unroll
    for (int off = 1; off < 64; off <<= 1) val += __shfl_xor(val, off);
    if ((h & 63) == 0) redv[h >> 6] = val;
    __syncthreads();
    if (h == 0) {
        float z = redv[0] + redv[1] + bc[0];
        out[b] = 1.f / (1.f + expf(-z));
    }
}

extern "C" void kernel_launch(void* const* d_in, const int* in_sizes, int n_in,
                              void* d_out, int out_size, void* d_ws, size_t ws_size,
                              hipStream_t stream) {
    const float* H    = (const float*)d_in[0];
    const int*   mask = (const int*)d_in[1];
    const float* W1   = (const float*)d_in[2];
    const float* b1   = (const float*)d_in[3];
    const float* W2   = (const float*)d_in[4];
    const float* b2   = (const float*)d_in[5];
    const float* Wc   = (const float*)d_in[6];
    const float* bc   = (const float*)d_in[7];
    float* out = (float*)d_out;

    const int NTOK = B * S;  // 32768

    // workspace layout (bytes)
    char* wsb = (char*)d_ws;
    short* Hb    = (short*)(wsb);                       // 48 MB
    short* y1    = (short*)(wsb);                       // overlays Hb (dead by then)
    unsigned char* Lbuf = (unsigned char*)(wsb + 50331648);  // 16 MB fp8
    short* xw1   = (short*)(wsb + 83886080);            // 16 MB, [tok][H1]
    float* rsum  = (float*)(wsb + 109051904);           // 32768 f
    float* wacc  = rsum + NTOK;                         // 32768 f
    float* emb   = wacc + NTOK;                         // 8192 f (zeroed with rsum/wacc)
    float* dis   = emb + 8192;                          // 32768 f
    short* W1T   = (short*)(dis + NTOK);                // 196608 el
    short* W2T   = W1T + 196608;                        // 32768 el
    uint_t* ents = (uint_t*)(wsb + 134217728);          // 64 MB
    uint_t* cnts = (uint_t*)(wsb + 201326592);          // 32768 u32

    // prologue: zero rsum+wacc+emb, cast weights (transposed), cast H
    k_cast<<<2048, 256, 0, stream>>>(H, Hb, W1, W1T, W2, W2T, rsum);

    // expL fp8 (full grid, XCD swizzle, swizzled LDS) + row sums
    k_logits<<<1024, 256, 0, stream>>>(Hb, Lbuf, rsum);

    // fused: prep (deg/dis/wacc/CSR) interleaved with UNSCALED xw1 GEMM
    k_prep_gemm<<<9216, 256, 0, stream>>>(Lbuf, rsum, mask, dis, wacc, ents, cnts,
                                          W1T, Hb, xw1);

    // sparse aggregation + relu + bias (CSR-driven, dis_i applied per entry)
    k_agg<<<4096, 256, 0, stream>>>(ents, cnts, dis, xw1, b1, y1);

    // emb[b][h2] += sum_t (y1 @ W2)[t][h2] * wacc[t]*dis[t]
    k_gemm_emb<<<512, 256, 0, stream>>>(W2T, y1, wacc, dis, emb);

    k_final<<<B, 128, 0, stream>>>(emb, mask, b2, Wc, bc, out);
}